// Round 6
// baseline (300.078 us; speedup 1.0000x reference)
//
#include <hip/hip_runtime.h>
#include <math.h>

#define Bq 4
#define Lq 2048
#define NH 8
#define LDP5 68   // attn Pp row stride (ushorts): 136B = 34 banks, gcd(34,32)=2 -> minimal aliasing

typedef __attribute__((ext_vector_type(8))) __bf16 bf16x8;
typedef __attribute__((ext_vector_type(4))) float f32x4;
#define MFMA16(a,b,c) __builtin_amdgcn_mfma_f32_16x16x32_bf16(a,b,c,0,0,0)

__device__ __forceinline__ void async16(const void* g, void* l) {
    __builtin_amdgcn_global_load_lds(
        (const __attribute__((address_space(1))) unsigned int*)g,
        (__attribute__((address_space(3))) unsigned int*)l, 16, 0, 0);
}

// truncation split: x = hi + lo (+ ~2^-16 rel residual)
__device__ __forceinline__ void splitbf(float x, ushort& h, ushort& l) {
    unsigned u = __float_as_uint(x);
    h = (ushort)(u >> 16);
    float hf = __uint_as_float(u & 0xffff0000u);
    l = (ushort)(__float_as_uint(x - hf) >> 16);
}
// round-to-nearest-even bf16
__device__ __forceinline__ ushort rnebf(float x) {
    unsigned u = __float_as_uint(x);
    return (ushort)((u + 0x7fffu + ((u >> 16) & 1u)) >> 16);
}

// ---- W [512k][512n] fp32 -> WT [z*512 + n][k] bf16 hi/lo planes ----
__global__ __launch_bounds__(256) void wsplit3_kernel(
    const float* __restrict__ W0, const float* __restrict__ W1, const float* __restrict__ W2,
    ushort* __restrict__ WTh, ushort* __restrict__ WTl)
{
    __shared__ float T[64][65];
    const int z = blockIdx.z;
    const float* W = (z == 0) ? W0 : (z == 1) ? W1 : W2;
    const int k0 = blockIdx.x * 64, n0 = blockIdx.y * 64;
    const int tid = threadIdx.x;
    #pragma unroll
    for (int i = 0; i < 4; ++i) {
        int u = tid + i * 256;
        int row = u >> 4, c4 = (u & 15) * 4;
        float4 v = *(const float4*)(W + (size_t)(k0 + row) * 512 + n0 + c4);
        T[row][c4 + 0] = v.x; T[row][c4 + 1] = v.y; T[row][c4 + 2] = v.z; T[row][c4 + 3] = v.w;
    }
    __syncthreads();
    #pragma unroll
    for (int i = 0; i < 2; ++i) {
        int u = tid + i * 256;
        int d = u >> 3, c8 = (u & 7) * 8;
        ushort hs[8], ls[8];
        #pragma unroll
        for (int j = 0; j < 8; ++j) splitbf(T[c8 + j][d], hs[j], ls[j]);
        uint4 wh, wl;
        wh.x = hs[0] | ((unsigned)hs[1] << 16); wh.y = hs[2] | ((unsigned)hs[3] << 16);
        wh.z = hs[4] | ((unsigned)hs[5] << 16); wh.w = hs[6] | ((unsigned)hs[7] << 16);
        wl.x = ls[0] | ((unsigned)ls[1] << 16); wl.y = ls[2] | ((unsigned)ls[3] << 16);
        wl.z = ls[4] | ((unsigned)ls[5] << 16); wl.w = ls[6] | ((unsigned)ls[7] << 16);
        size_t off = (size_t)(z * 512 + n0 + d) * 512 + k0 + c8;
        *(uint4*)(WTh + off) = wh;
        *(uint4*)(WTl + off) = wl;
    }
}

// ---- GEMM2: 128x64 tile, BK=32, 4 waves (64x32 each), dbuf async-B staging ----
// final_=0: mi = y>>3 selects 0->Q split planes, 1->K hi plane, 2->V^T split planes
// final_=1: fp32 out to Cf
union GS {
    struct {
        ushort Ah[2][128 * 40];
        ushort Al[2][128 * 40];
        ushort Bh[2][2048];
        ushort Bl[2][2048];
    } s;
    ushort E[57344 / 2];
};

__global__ __launch_bounds__(256) void gemm2_kernel(
    const float* __restrict__ A0, const float* __restrict__ A1, const float* __restrict__ A2,
    const ushort* __restrict__ BhT, const ushort* __restrict__ BlT,
    const float* __restrict__ b0, const float* __restrict__ b1, const float* __restrict__ b2,
    int final_, float* __restrict__ Cf,
    ushort* __restrict__ Qh, ushort* __restrict__ Ql, ushort* __restrict__ Khp,
    ushort* __restrict__ VhT, ushort* __restrict__ VlT)
{
    __shared__ __align__(16) GS gs;
    const int tid = threadIdx.x;
    const int wave = tid >> 6, lane = tid & 63;
    const int l15 = lane & 15, quad = lane >> 4;
    const int m0 = blockIdx.x * 128;
    const int yy = blockIdx.y;
    const int mi = yy >> 3, n0 = (yy & 7) * 64;
    const int nglob = mi * 512 + n0;
    const float* A = (mi == 0) ? A0 : (mi == 1) ? A1 : A2;
    const float* bias = (mi == 0) ? b0 : (mi == 1) ? b1 : b2;
    const int wm = (wave & 1) * 64, wn = (wave >> 1) * 32;

    // A staging (register path, needs splitbf): rows am+32i, chunk ak4
    const int am = tid >> 3, ak4 = (tid & 7) * 4;
    // B staging (async): wave stages rows wave*16..+15 of both planes, XOR-swizzled
    const int brow = lane >> 2, bsrc = (lane & 3) ^ (brow & 3);
    const ushort* bhp = BhT + (size_t)(nglob + wave * 16 + brow) * 512 + bsrc * 8;
    const ushort* blp = BlT + (size_t)(nglob + wave * 16 + brow) * 512 + bsrc * 8;
    const int bdst = wave * 512 + lane * 8;   // ushort idx; byte = uniform + lane*16

    f32x4 acc[4][2];
    #pragma unroll
    for (int i = 0; i < 4; ++i)
        #pragma unroll
        for (int j = 0; j < 2; ++j) acc[i][j] = (f32x4){0.f, 0.f, 0.f, 0.f};

    float4 av[4];
    #pragma unroll
    for (int i = 0; i < 4; ++i)
        av[i] = *(const float4*)(A + (size_t)(m0 + am + 32 * i) * 512 + ak4);
    async16(bhp, &gs.s.Bh[0][bdst]);
    async16(blp, &gs.s.Bl[0][bdst]);
    #pragma unroll
    for (int i = 0; i < 4; ++i) {
        ushort4 h4, l4;
        splitbf(av[i].x, h4.x, l4.x); splitbf(av[i].y, h4.y, l4.y);
        splitbf(av[i].z, h4.z, l4.z); splitbf(av[i].w, h4.w, l4.w);
        *(ushort4*)&gs.s.Ah[0][(am + 32 * i) * 40 + ak4] = h4;
        *(ushort4*)&gs.s.Al[0][(am + 32 * i) * 40 + ak4] = l4;
    }

    for (int t = 0; t < 16; ++t) {
        const int p = t & 1;
        __syncthreads();   // drains async B(t) + A writes(t); all reads of buf 1-p done
        if (t < 15) {
            const int kn = (t + 1) * 32;
            async16(bhp + kn, &gs.s.Bh[1 - p][bdst]);
            async16(blp + kn, &gs.s.Bl[1 - p][bdst]);
            #pragma unroll
            for (int i = 0; i < 4; ++i)
                av[i] = *(const float4*)(A + (size_t)(m0 + am + 32 * i) * 512 + kn + ak4);
        }
        bf16x8 afh[4], afl[4];
        #pragma unroll
        for (int ms = 0; ms < 4; ++ms) {
            int off = (wm + ms * 16 + l15) * 40 + quad * 8;
            afh[ms] = *(const bf16x8*)&gs.s.Ah[p][off];
            afl[ms] = *(const bf16x8*)&gs.s.Al[p][off];
        }
        #pragma unroll
        for (int ns = 0; ns < 2; ++ns) {
            int off = (wn + ns * 16 + l15) * 32 + (quad ^ (l15 & 3)) * 8;
            bf16x8 bfh = *(const bf16x8*)&gs.s.Bh[p][off];
            bf16x8 bfl = *(const bf16x8*)&gs.s.Bl[p][off];
            #pragma unroll
            for (int ms = 0; ms < 4; ++ms) {
                acc[ms][ns] = MFMA16(afh[ms], bfl, acc[ms][ns]);
                acc[ms][ns] = MFMA16(afl[ms], bfh, acc[ms][ns]);
                acc[ms][ns] = MFMA16(afh[ms], bfh, acc[ms][ns]);
            }
        }
        if (t < 15) {
            #pragma unroll
            for (int i = 0; i < 4; ++i) {
                ushort4 h4, l4;
                splitbf(av[i].x, h4.x, l4.x); splitbf(av[i].y, h4.y, l4.y);
                splitbf(av[i].z, h4.z, l4.z); splitbf(av[i].w, h4.w, l4.w);
                *(ushort4*)&gs.s.Ah[1 - p][(am + 32 * i) * 40 + ak4] = h4;
                *(ushort4*)&gs.s.Al[1 - p][(am + 32 * i) * 40 + ak4] = l4;
            }
        }
    }

    // bias
    #pragma unroll
    for (int ns = 0; ns < 2; ++ns) {
        float bv = bias[n0 + wn + ns * 16 + l15];
        #pragma unroll
        for (int ms = 0; ms < 4; ++ms)
            #pragma unroll
            for (int r = 0; r < 4; ++r) acc[ms][ns][r] += bv;
    }

    if (final_) {   // coalesced fp32 stores (16 lanes x 4B = 64B lines)
        #pragma unroll
        for (int ns = 0; ns < 2; ++ns) {
            int col = n0 + wn + ns * 16 + l15;
            #pragma unroll
            for (int ms = 0; ms < 4; ++ms)
                #pragma unroll
                for (int r = 0; r < 4; ++r)
                    Cf[(size_t)(m0 + wm + ms * 16 + quad * 4 + r) * 512 + col] = acc[ms][ns][r];
        }
        return;
    }

    const int h0 = n0 >> 6;
    const int b = m0 >> 11, rr0 = m0 & 2047;
    const int passes = (mi == 1) ? 1 : 2;
    for (int pass = 0; pass < passes; ++pass) {
        __syncthreads();
        // acc -> LDS (V: transposed [col][row], b64; Q/K: row-major [row][col], b16)
        #pragma unroll
        for (int ms = 0; ms < 4; ++ms) {
            #pragma unroll
            for (int ns = 0; ns < 2; ++ns) {
                int cl = wn + ns * 16 + l15;
                int rl = wm + ms * 16 + quad * 4;
                if (mi == 2) {
                    ushort4 w4;
                    #pragma unroll
                    for (int r = 0; r < 4; ++r) {
                        ushort h, l; splitbf(acc[ms][ns][r], h, l);
                        ((ushort*)&w4)[r] = pass ? l : h;
                    }
                    *(ushort4*)&gs.E[cl * 136 + rl] = w4;
                } else {
                    #pragma unroll
                    for (int r = 0; r < 4; ++r) {
                        float v = acc[ms][ns][r];
                        ushort out;
                        if (mi == 1) out = rnebf(v);
                        else { ushort h, l; splitbf(v, h, l); out = pass ? l : h; }
                        gs.E[(rl + r) * 72 + cl] = out;
                    }
                }
            }
        }
        __syncthreads();
        // LDS -> global, wide coalesced uint4
        if (mi == 2) {
            ushort* dst = pass ? VlT : VhT;
            #pragma unroll
            for (int i = 0; i < 4; ++i) {
                int idx = tid + i * 256;
                int d = idx >> 4, rg = idx & 15;
                uint4 u = *(const uint4*)&gs.E[d * 136 + rg * 8];
                *(uint4*)&dst[((size_t)(b * 8 + h0) * 64 + d) * 2048 + rr0 + rg * 8] = u;
            }
        } else {
            ushort* dst = (mi == 0) ? (pass ? Ql : Qh) : Khp;
            #pragma unroll
            for (int i = 0; i < 4; ++i) {
                int idx = tid + i * 256;
                int row = idx >> 3, cg = idx & 7;
                uint4 u = *(const uint4*)&gs.E[row * 72 + cg * 8];
                *(uint4*)&dst[((size_t)(b * 8 + h0) * 2048 + rr0 + row) * 64 + cg * 8] = u;
            }
        }
    }
}

// ---- Flash attention v5: counted-vmcnt 3-buffer pipeline (T3/T4) ----
// q-tile 256 (grid 32 x 8 = 256 blocks, 1/CU), kv-tile 64, 8 waves x 32 q-rows.
// Depth-2 prefetch, 3 LDS buffers: per iter t ->
//   s_waitcnt vmcnt(3)  (waits S(t); S(t+1) stays IN FLIGHT across the barrier)
//   raw s_barrier       (no compiler vmcnt(0) drain - the v4b stall)
//   load masks(t)       (issued BEFORE S(t+2) so mask-use waits don't drain it)
//   issue S(t+2)        (safe: all waves finished reading buf[(t+2)%3] = t-1's)
//   compute QK+softmax+PV (64 MFMA/wave)
// LDS: 3x24K KV + 35K Pp = 106 KB -> 1 block/CU; pipelining, not occupancy,
// is the lever (r3/r5 showed occupancy alone bought nothing).
struct SmemA {
    ushort KVs[3][3][4096];   // [buf][K,Vh,Vl][64x64 bf16], 73728 B
    ushort Pp[8][32 * LDP5];  // per-wave P rows, 34816 B
};

__global__ __launch_bounds__(512, 2) void attn3_kernel(
    const ushort* __restrict__ Qh, const ushort* __restrict__ Ql,
    const ushort* __restrict__ Kh, const ushort* __restrict__ VhT,
    const ushort* __restrict__ VlT, const int* __restrict__ mask,
    float* __restrict__ XS)
{
    __shared__ __align__(16) SmemA smem;
    const int tid = threadIdx.x;
    const int wave = tid >> 6, lane = tid & 63;
    const int l15 = lane & 15, quad = lane >> 4;
    const int bh = blockIdx.x, b = bh >> 3, h = bh & 7;
    const int q0 = blockIdx.y * 256;

    // staging: 3 async16 per thread per t (24 KB/t). Sub-buffers of 512 slots:
    // j=0: K [64 kv][8 chunks], j=1/2: V^T planes [64 d][8 chunks], chunk ^= row&7
    const int srow = tid >> 3, sc = ((tid & 7) ^ (srow & 7)) * 8;
    const ushort* sp[3]; int sstp[3];
    sp[0] = Kh  + ((size_t)(bh * 2048 + srow)) * 64 + sc;   sstp[0] = 64 * 64;
    sp[1] = VhT + ((size_t)(bh * 64 + srow)) * 2048 + sc;   sstp[1] = 64;
    sp[2] = VlT + ((size_t)(bh * 64 + srow)) * 2048 + sc;   sstp[2] = 64;
    const int dofs = tid * 8;   // within each 4096-ushort sub-buffer

    // prologue: S(0), S(1) in flight
    #pragma unroll
    for (int j = 0; j < 3; ++j)
        async16(sp[j], &smem.KVs[0][j][dofs]);
    #pragma unroll
    for (int j = 0; j < 3; ++j)
        async16(sp[j] + sstp[j], &smem.KVs[1][j][dofs]);

    bf16x8 qhf[2][2], qlf[2][2];
    #pragma unroll
    for (int qs = 0; qs < 2; ++qs) {
        size_t qb = ((size_t)bh * 2048 + q0 + wave * 32 + qs * 16 + l15) * 64 + quad * 8;
        qhf[qs][0] = *(const bf16x8*)(Qh + qb);
        qhf[qs][1] = *(const bf16x8*)(Qh + qb + 32);
        qlf[qs][0] = *(const bf16x8*)(Ql + qb);
        qlf[qs][1] = *(const bf16x8*)(Ql + qb + 32);
    }

    const f32x4 z = {0.f, 0.f, 0.f, 0.f};
    f32x4 oacc[2][4];
    #pragma unroll
    for (int i = 0; i < 2; ++i)
        #pragma unroll
        for (int j = 0; j < 4; ++j) oacc[i][j] = z;
    float lacc[2] = {0.f, 0.f};

    const int mrow0 = b * 2048;
    const int sw = (quad ^ (l15 & 7)) * 8;   // K/V tile read swizzle
    ushort* Pw = smem.Pp[wave];

    for (int t = 0; t < 32; ++t) {
        // wait own S(t) done (3 = S(t+1) loads stay outstanding); final iter drains
        if (t < 31) asm volatile("s_waitcnt vmcnt(3)" ::: "memory");
        else        asm volatile("s_waitcnt vmcnt(0)" ::: "memory");
        __builtin_amdgcn_s_barrier();   // raw: no vmcnt(0) drain
        // masks first: their compiler-inserted waits then allow 3 outstanding
        int4 mv[4];
        #pragma unroll
        for (int kt = 0; kt < 4; ++kt)
            mv[kt] = *(const int4*)(mask + mrow0 + t * 64 + kt * 16 + quad * 4);
        if (t < 30) {
            #pragma unroll
            for (int j = 0; j < 3; ++j)
                async16(sp[j] + (size_t)(t + 2) * sstp[j], &smem.KVs[(t + 2) % 3][j][dofs]);
        }
        const ushort* K0 = smem.KVs[t % 3][0];
        const ushort* V0 = smem.KVs[t % 3][1];
        const ushort* V1 = smem.KVs[t % 3][2];

        #pragma unroll
        for (int kt = 0; kt < 4; ++kt) {
            const int kb = (kt * 16 + l15) * 64;
            bf16x8 ka0 = *(const bf16x8*)&K0[kb + sw];
            bf16x8 ka1 = *(const bf16x8*)&K0[kb + (sw ^ 32)];
            float bias[4];
            bias[0] = mv[kt].x ? 0.f : -1e30f; bias[1] = mv[kt].y ? 0.f : -1e30f;
            bias[2] = mv[kt].z ? 0.f : -1e30f; bias[3] = mv[kt].w ? 0.f : -1e30f;
            #pragma unroll
            for (int qs = 0; qs < 2; ++qs) {
                f32x4 a = z;
                a = MFMA16(ka0, qlf[qs][0], a);
                a = MFMA16(ka1, qlf[qs][1], a);
                a = MFMA16(ka0, qhf[qs][0], a);
                a = MFMA16(ka1, qhf[qs][1], a);
                ushort4 hv;
                #pragma unroll
                for (int r = 0; r < 4; ++r) {
                    float pv = __expf(a[r] * 0.125f + bias[r]);
                    unsigned u = __float_as_uint(pv);
                    unsigned hu = (u + 0x7fffu + ((u >> 16) & 1u)) & 0xffff0000u;
                    lacc[qs] += __uint_as_float(hu);
                    ((ushort*)&hv)[r] = (ushort)(hu >> 16);
                }
                *(ushort4*)&Pw[(qs * 16 + l15) * LDP5 + kt * 16 + quad * 4] = hv;
            }
        }
        #pragma unroll
        for (int ks = 0; ks < 2; ++ks) {
            bf16x8 pf[2];
            #pragma unroll
            for (int qs = 0; qs < 2; ++qs)
                pf[qs] = *(const bf16x8*)&Pw[(qs * 16 + l15) * LDP5 + ks * 32 + quad * 8];
            const int svo = sw ^ (ks * 32);
            #pragma unroll
            for (int dsub = 0; dsub < 4; ++dsub) {
                const int vb = (dsub * 16 + l15) * 64;
                bf16x8 vh = *(const bf16x8*)&V0[vb + svo];
                bf16x8 vl = *(const bf16x8*)&V1[vb + svo];
                #pragma unroll
                for (int qs = 0; qs < 2; ++qs) {
                    oacc[qs][dsub] = MFMA16(vl, pf[qs], oacc[qs][dsub]);
                    oacc[qs][dsub] = MFMA16(vh, pf[qs], oacc[qs][dsub]);
                }
            }
        }
    }

    // row-sum across the 4 quads holding this q row's kv partials
    #pragma unroll
    for (int qs = 0; qs < 2; ++qs) {
        float lv = lacc[qs];
        lv += __shfl_xor(lv, 16);
        lv += __shfl_xor(lv, 32);
        float inv = (lv > 0.f) ? 1.f / lv : 0.f;

        const int row = q0 + wave * 32 + qs * 16 + l15;
        float* rowp = XS + ((size_t)(b * 2048 + row)) * 512 + h * 64;
        #pragma unroll
        for (int dsub = 0; dsub < 4; ++dsub) {
            float4 o4;
            o4.x = oacc[qs][dsub][0] * inv;
            o4.y = oacc[qs][dsub][1] * inv;
            o4.z = oacc[qs][dsub][2] * inv;
            o4.w = oacc[qs][dsub][3] * inv;
            *(float4*)(rowp + dsub * 16 + quad * 4) = o4;
        }
    }
}

extern "C" void kernel_launch(void* const* d_in, const int* in_sizes, int n_in,
                              void* d_out, int out_size, void* d_ws, size_t ws_size,
                              hipStream_t stream) {
    const float* query = (const float*)d_in[0];
    const float* key   = (const float*)d_in[1];
    const float* value = (const float*)d_in[2];
    const int*   mask  = (const int*)d_in[3];
    const float* Wq = (const float*)d_in[4];
    const float* bq = (const float*)d_in[5];
    const float* Wk = (const float*)d_in[6];
    const float* bk = (const float*)d_in[7];
    const float* Wv = (const float*)d_in[8];
    const float* bv = (const float*)d_in[9];
    const float* Wo = (const float*)d_in[10];
    const float* bo = (const float*)d_in[11];

    char* w = (char*)d_ws;
    const size_t MB = (size_t)1 << 20;
    ushort* Qh  = (ushort*)(w + 0 * MB);
    ushort* Ql  = (ushort*)(w + 8 * MB);
    ushort* Khp = (ushort*)(w + 16 * MB);
    ushort* VhT = (ushort*)(w + 24 * MB);
    ushort* VlT = (ushort*)(w + 32 * MB);
    float*  XS  = (float*)(w + 40 * MB);          // 16 MB fp32
    ushort* WTh = (ushort*)(w + 56 * MB);          // [1536][512]
    ushort* WTl = WTh + (size_t)1536 * 512;
    // Wo planes reuse the Qh region (dead after attn3)
    ushort* WoTh = (ushort*)(w + 0 * MB);
    ushort* WoTl = WoTh + (size_t)512 * 512;

    wsplit3_kernel<<<dim3(8, 8, 3), 256, 0, stream>>>(Wq, Wk, Wv, WTh, WTl);
    gemm2_kernel<<<dim3(64, 24), 256, 0, stream>>>(
        query, key, value, WTh, WTl, bq, bk, bv, 0, nullptr, Qh, Ql, Khp, VhT, VlT);
    attn3_kernel<<<dim3(32, 8), 512, 0, stream>>>(Qh, Ql, Khp, VhT, VlT, mask, XS);
    wsplit3_kernel<<<dim3(8, 8, 1), 256, 0, stream>>>(Wo, Wo, Wo, WoTh, WoTl);
    gemm2_kernel<<<dim3(64, 8), 256, 0, stream>>>(
        XS, XS, XS, WoTh, WoTl, bo, bo, bo, 1, (float*)d_out,
        nullptr, nullptr, nullptr, nullptr, nullptr);
}

// Round 7
// 280.681 us; speedup vs baseline: 1.0691x; 1.0691x over previous
//
#include <hip/hip_runtime.h>
#include <math.h>

#define Bq 4
#define Lq 2048
#define NH 8
#define LDP6 36   // attn Pp row stride (ushorts): 72B = 18 banks, gcd(18,32)=2 -> conflict-free (r3-verified)

typedef __attribute__((ext_vector_type(8))) __bf16 bf16x8;
typedef __attribute__((ext_vector_type(4))) float f32x4;
#define MFMA16(a,b,c) __builtin_amdgcn_mfma_f32_16x16x32_bf16(a,b,c,0,0,0)

__device__ __forceinline__ void async16(const void* g, void* l) {
    __builtin_amdgcn_global_load_lds(
        (const __attribute__((address_space(1))) unsigned int*)g,
        (__attribute__((address_space(3))) unsigned int*)l, 16, 0, 0);
}

// truncation split: x = hi + lo (+ ~2^-16 rel residual)
__device__ __forceinline__ void splitbf(float x, ushort& h, ushort& l) {
    unsigned u = __float_as_uint(x);
    h = (ushort)(u >> 16);
    float hf = __uint_as_float(u & 0xffff0000u);
    l = (ushort)(__float_as_uint(x - hf) >> 16);
}
// round-to-nearest-even bf16
__device__ __forceinline__ ushort rnebf(float x) {
    unsigned u = __float_as_uint(x);
    return (ushort)((u + 0x7fffu + ((u >> 16) & 1u)) >> 16);
}

// ---- W [512k][512n] fp32 -> WT [z*512 + n][k] bf16 hi/lo planes ----
__global__ __launch_bounds__(256) void wsplit3_kernel(
    const float* __restrict__ W0, const float* __restrict__ W1, const float* __restrict__ W2,
    ushort* __restrict__ WTh, ushort* __restrict__ WTl)
{
    __shared__ float T[64][65];
    const int z = blockIdx.z;
    const float* W = (z == 0) ? W0 : (z == 1) ? W1 : W2;
    const int k0 = blockIdx.x * 64, n0 = blockIdx.y * 64;
    const int tid = threadIdx.x;
    #pragma unroll
    for (int i = 0; i < 4; ++i) {
        int u = tid + i * 256;
        int row = u >> 4, c4 = (u & 15) * 4;
        float4 v = *(const float4*)(W + (size_t)(k0 + row) * 512 + n0 + c4);
        T[row][c4 + 0] = v.x; T[row][c4 + 1] = v.y; T[row][c4 + 2] = v.z; T[row][c4 + 3] = v.w;
    }
    __syncthreads();
    #pragma unroll
    for (int i = 0; i < 2; ++i) {
        int u = tid + i * 256;
        int d = u >> 3, c8 = (u & 7) * 8;
        ushort hs[8], ls[8];
        #pragma unroll
        for (int j = 0; j < 8; ++j) splitbf(T[c8 + j][d], hs[j], ls[j]);
        uint4 wh, wl;
        wh.x = hs[0] | ((unsigned)hs[1] << 16); wh.y = hs[2] | ((unsigned)hs[3] << 16);
        wh.z = hs[4] | ((unsigned)hs[5] << 16); wh.w = hs[6] | ((unsigned)hs[7] << 16);
        wl.x = ls[0] | ((unsigned)ls[1] << 16); wl.y = ls[2] | ((unsigned)ls[3] << 16);
        wl.z = ls[4] | ((unsigned)ls[5] << 16); wl.w = ls[6] | ((unsigned)ls[7] << 16);
        size_t off = (size_t)(z * 512 + n0 + d) * 512 + k0 + c8;
        *(uint4*)(WTh + off) = wh;
        *(uint4*)(WTl + off) = wl;
    }
}

// ---- GEMM2: 128x64 tile, BK=32, 4 waves (64x32 each), dbuf async-B staging ----
// final_=0: mi = y>>3 selects 0->Q split planes, 1->K hi plane, 2->V^T split planes
// final_=1: fp32 out to Cf
union GS {
    struct {
        ushort Ah[2][128 * 40];
        ushort Al[2][128 * 40];
        ushort Bh[2][2048];
        ushort Bl[2][2048];
    } s;
    ushort E[57344 / 2];
};

__global__ __launch_bounds__(256) void gemm2_kernel(
    const float* __restrict__ A0, const float* __restrict__ A1, const float* __restrict__ A2,
    const ushort* __restrict__ BhT, const ushort* __restrict__ BlT,
    const float* __restrict__ b0, const float* __restrict__ b1, const float* __restrict__ b2,
    int final_, float* __restrict__ Cf,
    ushort* __restrict__ Qh, ushort* __restrict__ Ql, ushort* __restrict__ Khp,
    ushort* __restrict__ VhT, ushort* __restrict__ VlT)
{
    __shared__ __align__(16) GS gs;
    const int tid = threadIdx.x;
    const int wave = tid >> 6, lane = tid & 63;
    const int l15 = lane & 15, quad = lane >> 4;
    const int m0 = blockIdx.x * 128;
    const int yy = blockIdx.y;
    const int mi = yy >> 3, n0 = (yy & 7) * 64;
    const int nglob = mi * 512 + n0;
    const float* A = (mi == 0) ? A0 : (mi == 1) ? A1 : A2;
    const float* bias = (mi == 0) ? b0 : (mi == 1) ? b1 : b2;
    const int wm = (wave & 1) * 64, wn = (wave >> 1) * 32;

    // A staging (register path, needs splitbf): rows am+32i, chunk ak4
    const int am = tid >> 3, ak4 = (tid & 7) * 4;
    // B staging (async): wave stages rows wave*16..+15 of both planes, XOR-swizzled
    const int brow = lane >> 2, bsrc = (lane & 3) ^ (brow & 3);
    const ushort* bhp = BhT + (size_t)(nglob + wave * 16 + brow) * 512 + bsrc * 8;
    const ushort* blp = BlT + (size_t)(nglob + wave * 16 + brow) * 512 + bsrc * 8;
    const int bdst = wave * 512 + lane * 8;   // ushort idx; byte = uniform + lane*16

    f32x4 acc[4][2];
    #pragma unroll
    for (int i = 0; i < 4; ++i)
        #pragma unroll
        for (int j = 0; j < 2; ++j) acc[i][j] = (f32x4){0.f, 0.f, 0.f, 0.f};

    float4 av[4];
    #pragma unroll
    for (int i = 0; i < 4; ++i)
        av[i] = *(const float4*)(A + (size_t)(m0 + am + 32 * i) * 512 + ak4);
    async16(bhp, &gs.s.Bh[0][bdst]);
    async16(blp, &gs.s.Bl[0][bdst]);
    #pragma unroll
    for (int i = 0; i < 4; ++i) {
        ushort4 h4, l4;
        splitbf(av[i].x, h4.x, l4.x); splitbf(av[i].y, h4.y, l4.y);
        splitbf(av[i].z, h4.z, l4.z); splitbf(av[i].w, h4.w, l4.w);
        *(ushort4*)&gs.s.Ah[0][(am + 32 * i) * 40 + ak4] = h4;
        *(ushort4*)&gs.s.Al[0][(am + 32 * i) * 40 + ak4] = l4;
    }

    for (int t = 0; t < 16; ++t) {
        const int p = t & 1;
        __syncthreads();   // drains async B(t) + A writes(t); all reads of buf 1-p done
        if (t < 15) {
            const int kn = (t + 1) * 32;
            async16(bhp + kn, &gs.s.Bh[1 - p][bdst]);
            async16(blp + kn, &gs.s.Bl[1 - p][bdst]);
            #pragma unroll
            for (int i = 0; i < 4; ++i)
                av[i] = *(const float4*)(A + (size_t)(m0 + am + 32 * i) * 512 + kn + ak4);
        }
        bf16x8 afh[4], afl[4];
        #pragma unroll
        for (int ms = 0; ms < 4; ++ms) {
            int off = (wm + ms * 16 + l15) * 40 + quad * 8;
            afh[ms] = *(const bf16x8*)&gs.s.Ah[p][off];
            afl[ms] = *(const bf16x8*)&gs.s.Al[p][off];
        }
        #pragma unroll
        for (int ns = 0; ns < 2; ++ns) {
            int off = (wn + ns * 16 + l15) * 32 + (quad ^ (l15 & 3)) * 8;
            bf16x8 bfh = *(const bf16x8*)&gs.s.Bh[p][off];
            bf16x8 bfl = *(const bf16x8*)&gs.s.Bl[p][off];
            #pragma unroll
            for (int ms = 0; ms < 4; ++ms) {
                acc[ms][ns] = MFMA16(afh[ms], bfl, acc[ms][ns]);
                acc[ms][ns] = MFMA16(afl[ms], bfh, acc[ms][ns]);
                acc[ms][ns] = MFMA16(afh[ms], bfh, acc[ms][ns]);
            }
        }
        if (t < 15) {
            #pragma unroll
            for (int i = 0; i < 4; ++i) {
                ushort4 h4, l4;
                splitbf(av[i].x, h4.x, l4.x); splitbf(av[i].y, h4.y, l4.y);
                splitbf(av[i].z, h4.z, l4.z); splitbf(av[i].w, h4.w, l4.w);
                *(ushort4*)&gs.s.Ah[1 - p][(am + 32 * i) * 40 + ak4] = h4;
                *(ushort4*)&gs.s.Al[1 - p][(am + 32 * i) * 40 + ak4] = l4;
            }
        }
    }

    // bias
    #pragma unroll
    for (int ns = 0; ns < 2; ++ns) {
        float bv = bias[n0 + wn + ns * 16 + l15];
        #pragma unroll
        for (int ms = 0; ms < 4; ++ms)
            #pragma unroll
            for (int r = 0; r < 4; ++r) acc[ms][ns][r] += bv;
    }

    if (final_) {   // coalesced fp32 stores (16 lanes x 4B = 64B lines)
        #pragma unroll
        for (int ns = 0; ns < 2; ++ns) {
            int col = n0 + wn + ns * 16 + l15;
            #pragma unroll
            for (int ms = 0; ms < 4; ++ms)
                #pragma unroll
                for (int r = 0; r < 4; ++r)
                    Cf[(size_t)(m0 + wm + ms * 16 + quad * 4 + r) * 512 + col] = acc[ms][ns][r];
        }
        return;
    }

    const int h0 = n0 >> 6;
    const int b = m0 >> 11, rr0 = m0 & 2047;
    const int passes = (mi == 1) ? 1 : 2;
    for (int pass = 0; pass < passes; ++pass) {
        __syncthreads();
        // acc -> LDS (V: transposed [col][row], b64; Q/K: row-major [row][col], b16)
        #pragma unroll
        for (int ms = 0; ms < 4; ++ms) {
            #pragma unroll
            for (int ns = 0; ns < 2; ++ns) {
                int cl = wn + ns * 16 + l15;
                int rl = wm + ms * 16 + quad * 4;
                if (mi == 2) {
                    ushort4 w4;
                    #pragma unroll
                    for (int r = 0; r < 4; ++r) {
                        ushort h, l; splitbf(acc[ms][ns][r], h, l);
                        ((ushort*)&w4)[r] = pass ? l : h;
                    }
                    *(ushort4*)&gs.E[cl * 136 + rl] = w4;
                } else {
                    #pragma unroll
                    for (int r = 0; r < 4; ++r) {
                        float v = acc[ms][ns][r];
                        ushort out;
                        if (mi == 1) out = rnebf(v);
                        else { ushort h, l; splitbf(v, h, l); out = pass ? l : h; }
                        gs.E[(rl + r) * 72 + cl] = out;
                    }
                }
            }
        }
        __syncthreads();
        // LDS -> global, wide coalesced uint4
        if (mi == 2) {
            ushort* dst = pass ? VlT : VhT;
            #pragma unroll
            for (int i = 0; i < 4; ++i) {
                int idx = tid + i * 256;
                int d = idx >> 4, rg = idx & 15;
                uint4 u = *(const uint4*)&gs.E[d * 136 + rg * 8];
                *(uint4*)&dst[((size_t)(b * 8 + h0) * 64 + d) * 2048 + rr0 + rg * 8] = u;
            }
        } else {
            ushort* dst = (mi == 0) ? (pass ? Ql : Qh) : Khp;
            #pragma unroll
            for (int i = 0; i < 4; ++i) {
                int idx = tid + i * 256;
                int row = idx >> 3, cg = idx & 7;
                uint4 u = *(const uint4*)&gs.E[row * 72 + cg * 8];
                *(uint4*)&dst[((size_t)(b * 8 + h0) * 2048 + rr0 + row) * 64 + cg * 8] = u;
            }
        }
    }
}

// ---- Flash attention (r0 structure + fast softmax) ----
// S^T dataflow, in-block split-K, async dbuf, 512 threads, 16 barriers.
// Softmax path per P-element: 1 fma (score*0.125*log2e + mask bias, log2
// domain) + 1 v_exp_f32 + 1 lacc add; bf16 pack via v_cvt_pk_bf16_f32 (1 per
// 2 elems). Replaces ~12-inst __expf + RNE-round + pack chain (VALU was 41%
// busy = largest pipe at r0). lacc sums unrounded p (better denominator).
// Pp stride 40 -> 36 (72B = 18 banks, gcd 2): kills r0's 3.9M conflict cycles.
union SmemU {
    struct { ushort KVs[2][6][4096]; ushort Pp[8][64 * LDP6]; } p1;
    struct { float Obuf[4][64 * 68]; float Lbuf[4][64]; } p2;
};

__global__ __launch_bounds__(512, 2) void attn3_kernel(
    const ushort* __restrict__ Qh, const ushort* __restrict__ Ql,
    const ushort* __restrict__ Kh, const ushort* __restrict__ VhT,
    const ushort* __restrict__ VlT, const int* __restrict__ mask,
    float* __restrict__ XS)
{
    __shared__ SmemU smem;
    const int tid = threadIdx.x;
    const int wave = tid >> 6, lane = tid & 63;
    const int l15 = lane & 15, quad = lane >> 4;
    const int w4 = wave & 3, half = wave >> 2;
    const int bh = blockIdx.x, b = bh >> 3, h = bh & 7;
    const int q0 = blockIdx.y * 256;

    bf16x8 qh[4][2], ql[4][2];
    #pragma unroll
    for (int qs = 0; qs < 4; ++qs) {
        size_t qb = ((size_t)bh * 2048 + q0 + w4 * 64 + qs * 16 + l15) * 64 + quad * 8;
        qh[qs][0] = *(const bf16x8*)(Qh + qb);
        qh[qs][1] = *(const bf16x8*)(Qh + qb + 32);
        ql[qs][0] = *(const bf16x8*)(Ql + qb);
        ql[qs][1] = *(const bf16x8*)(Ql + qb + 32);
    }

    const f32x4 z = {0.f, 0.f, 0.f, 0.f};
    f32x4 oacc[4][4];
    #pragma unroll
    for (int i = 0; i < 4; ++i)
        #pragma unroll
        for (int j = 0; j < 4; ++j) oacc[i][j] = z;
    float lacc[4] = {0.f, 0.f, 0.f, 0.f};

    const int rloc = lane >> 3, gs = (lane & 7) ^ rloc;
    const ushort* sb[6]; size_t sstep[6]; int dofs[6];
    #pragma unroll
    for (int i = 0; i < 6; ++i) {
        int cc = wave * 6 + i;
        int hc = cc / 24, r24 = cc % 24, pc = r24 >> 3, ic = r24 & 7;
        if (pc == 0) {
            sb[i] = Kh + ((size_t)(bh * 2048 + hc * 1024 + ic * 8 + rloc)) * 64 + gs * 8;
            sstep[i] = (size_t)64 * 64;
        } else {
            const ushort* vp = (pc == 1) ? VhT : VlT;
            sb[i] = vp + ((size_t)(bh * 64 + ic * 8 + rloc)) * 2048 + hc * 1024 + gs * 8;
            sstep[i] = 64;
        }
        dofs[i] = (hc * 3 + pc) * 4096 + ic * 512;
    }

    const int sw0 = (quad ^ (l15 & 7)) * 8;
    const int mrow0 = b * 2048 + half * 1024;
    const float SCL = 0.18033688011112042f;   // 0.125 * log2(e)

    #pragma unroll
    for (int i = 0; i < 6; ++i)
        async16(sb[i], &smem.p1.KVs[0][0][0] + dofs[i]);

    for (int t = 0; t < 16; ++t) {
        __syncthreads();
        if (t < 15) {
            #pragma unroll
            for (int i = 0; i < 6; ++i)
                async16(sb[i] + (size_t)(t + 1) * sstep[i], &smem.p1.KVs[(t + 1) & 1][0][0] + dofs[i]);
        }
        const int p = t & 1;
        const ushort* K0 = smem.p1.KVs[p][half * 3 + 0];
        const ushort* V0 = smem.p1.KVs[p][half * 3 + 1];
        const ushort* V1 = smem.p1.KVs[p][half * 3 + 2];
        ushort* Pw = smem.p1.Pp[wave];

        #pragma unroll
        for (int ks = 0; ks < 2; ++ks) {
            #pragma unroll
            for (int kt2 = 0; kt2 < 2; ++kt2) {
                const int kt = ks * 2 + kt2;
                const int kb = (kt * 16 + l15) * 64;
                bf16x8 ka0 = *(const bf16x8*)&K0[kb + sw0];
                bf16x8 ka1 = *(const bf16x8*)&K0[kb + (sw0 ^ 32)];
                int4 mv = *(const int4*)(mask + mrow0 + t * 64 + kt * 16 + quad * 4);
                float bias[4];   // log2-domain mask bias
                bias[0] = mv.x ? 0.f : -1e38f; bias[1] = mv.y ? 0.f : -1e38f;
                bias[2] = mv.z ? 0.f : -1e38f; bias[3] = mv.w ? 0.f : -1e38f;
                #pragma unroll
                for (int qs = 0; qs < 4; ++qs) {
                    f32x4 a = z;
                    a = MFMA16(ka0, ql[qs][0], a);
                    a = MFMA16(ka1, ql[qs][1], a);
                    a = MFMA16(ka0, qh[qs][0], a);
                    a = MFMA16(ka1, qh[qs][1], a);
                    float pv[4];
                    #pragma unroll
                    for (int r = 0; r < 4; ++r) {
                        float x = __builtin_fmaf(a[r], SCL, bias[r]);
                        float e; asm("v_exp_f32 %0, %1" : "=v"(e) : "v"(x));
                        lacc[qs] += e;
                        pv[r] = e;
                    }
                    unsigned u01, u23;
                    asm("v_cvt_pk_bf16_f32 %0, %1, %2" : "=v"(u01) : "v"(pv[0]), "v"(pv[1]));
                    asm("v_cvt_pk_bf16_f32 %0, %1, %2" : "=v"(u23) : "v"(pv[2]), "v"(pv[3]));
                    uint2 w2; w2.x = u01; w2.y = u23;
                    *(uint2*)&Pw[(qs * 16 + l15) * LDP6 + kt2 * 16 + quad * 4] = w2;
                }
            }
            const int svo = sw0 ^ (ks * 32);
            bf16x8 pf[4];
            #pragma unroll
            for (int qs = 0; qs < 4; ++qs)
                pf[qs] = *(const bf16x8*)&Pw[(qs * 16 + l15) * LDP6 + quad * 8];
            #pragma unroll
            for (int dsub = 0; dsub < 4; ++dsub) {
                const int vb = (dsub * 16 + l15) * 64;
                bf16x8 vh = *(const bf16x8*)&V0[vb + svo];
                bf16x8 vl = *(const bf16x8*)&V1[vb + svo];
                #pragma unroll
                for (int qs = 0; qs < 4; ++qs) {
                    oacc[qs][dsub] = MFMA16(vl, pf[qs], oacc[qs][dsub]);
                    oacc[qs][dsub] = MFMA16(vh, pf[qs], oacc[qs][dsub]);
                }
            }
        }
    }

    float lv[4];
    #pragma unroll
    for (int qs = 0; qs < 4; ++qs) {
        float v = lacc[qs];
        v += __shfl_xor(v, 16);
        v += __shfl_xor(v, 32);
        lv[qs] = v;
    }

    __syncthreads();
    if (half == 1) {
        #pragma unroll
        for (int qs = 0; qs < 4; ++qs) {
            #pragma unroll
            for (int dsub = 0; dsub < 4; ++dsub) {
                float4 o4 = {oacc[qs][dsub][0], oacc[qs][dsub][1], oacc[qs][dsub][2], oacc[qs][dsub][3]};
                *(float4*)&smem.p2.Obuf[w4][(qs * 16 + l15) * 68 + dsub * 16 + quad * 4] = o4;
            }
            if (quad == 0) smem.p2.Lbuf[w4][qs * 16 + l15] = lv[qs];
        }
    }
    __syncthreads();
    if (half == 0) {
        #pragma unroll
        for (int qs = 0; qs < 4; ++qs) {
            float ltot = lv[qs] + smem.p2.Lbuf[w4][qs * 16 + l15];
            float inv = (ltot > 0.f) ? 1.f / ltot : 0.f;
            int row = q0 + w4 * 64 + qs * 16 + l15;
            float* rowp = XS + ((size_t)(b * 2048 + row)) * 512 + h * 64;
            #pragma unroll
            for (int dsub = 0; dsub < 4; ++dsub) {
                float4 p4 = *(const float4*)&smem.p2.Obuf[w4][(qs * 16 + l15) * 68 + dsub * 16 + quad * 4];
                float4 o4;
                o4.x = (oacc[qs][dsub][0] + p4.x) * inv;
                o4.y = (oacc[qs][dsub][1] + p4.y) * inv;
                o4.z = (oacc[qs][dsub][2] + p4.z) * inv;
                o4.w = (oacc[qs][dsub][3] + p4.w) * inv;
                *(float4*)(rowp + dsub * 16 + quad * 4) = o4;
            }
        }
    }
}

extern "C" void kernel_launch(void* const* d_in, const int* in_sizes, int n_in,
                              void* d_out, int out_size, void* d_ws, size_t ws_size,
                              hipStream_t stream) {
    const float* query = (const float*)d_in[0];
    const float* key   = (const float*)d_in[1];
    const float* value = (const float*)d_in[2];
    const int*   mask  = (const int*)d_in[3];
    const float* Wq = (const float*)d_in[4];
    const float* bq = (const float*)d_in[5];
    const float* Wk = (const float*)d_in[6];
    const float* bk = (const float*)d_in[7];
    const float* Wv = (const float*)d_in[8];
    const float* bv = (const float*)d_in[9];
    const float* Wo = (const float*)d_in[10];
    const float* bo = (const float*)d_in[11];

    char* w = (char*)d_ws;
    const size_t MB = (size_t)1 << 20;
    ushort* Qh  = (ushort*)(w + 0 * MB);
    ushort* Ql  = (ushort*)(w + 8 * MB);
    ushort* Khp = (ushort*)(w + 16 * MB);
    ushort* VhT = (ushort*)(w + 24 * MB);
    ushort* VlT = (ushort*)(w + 32 * MB);
    float*  XS  = (float*)(w + 40 * MB);          // 16 MB fp32
    ushort* WTh = (ushort*)(w + 56 * MB);          // [1536][512]
    ushort* WTl = WTh + (size_t)1536 * 512;
    // Wo planes reuse the Qh region (dead after attn3)
    ushort* WoTh = (ushort*)(w + 0 * MB);
    ushort* WoTl = WoTh + (size_t)512 * 512;

    wsplit3_kernel<<<dim3(8, 8, 3), 256, 0, stream>>>(Wq, Wk, Wv, WTh, WTl);
    gemm2_kernel<<<dim3(64, 24), 256, 0, stream>>>(
        query, key, value, WTh, WTl, bq, bk, bv, 0, nullptr, Qh, Ql, Khp, VhT, VlT);
    attn3_kernel<<<dim3(32, 8), 512, 0, stream>>>(Qh, Ql, Khp, VhT, VlT, mask, XS);
    wsplit3_kernel<<<dim3(8, 8, 1), 256, 0, stream>>>(Wo, Wo, Wo, WoTh, WoTl);
    gemm2_kernel<<<dim3(64, 8), 256, 0, stream>>>(
        XS, XS, XS, WoTh, WoTl, bo, bo, bo, 1, (float*)d_out,
        nullptr, nullptr, nullptr, nullptr, nullptr);
}

// Round 8
// 280.040 us; speedup vs baseline: 1.0716x; 1.0023x over previous
//
#include <hip/hip_runtime.h>
#include <math.h>

#define Bq 4
#define Lq 2048
#define NH 8
#define LDP6 36   // attn Pp row stride (ushorts): 72B = 18 banks, gcd(18,32)=2 -> conflict-free (r3-verified)

typedef __attribute__((ext_vector_type(8))) __bf16 bf16x8;
typedef __attribute__((ext_vector_type(4))) float f32x4;
#define MFMA16(a,b,c) __builtin_amdgcn_mfma_f32_16x16x32_bf16(a,b,c,0,0,0)

__device__ __forceinline__ void async16(const void* g, void* l) {
    __builtin_amdgcn_global_load_lds(
        (const __attribute__((address_space(1))) unsigned int*)g,
        (__attribute__((address_space(3))) unsigned int*)l, 16, 0, 0);
}

// truncation split: x = hi + lo (+ ~2^-16 rel residual)
__device__ __forceinline__ void splitbf(float x, ushort& h, ushort& l) {
    unsigned u = __float_as_uint(x);
    h = (ushort)(u >> 16);
    float hf = __uint_as_float(u & 0xffff0000u);
    l = (ushort)(__float_as_uint(x - hf) >> 16);
}
// round-to-nearest-even bf16
__device__ __forceinline__ ushort rnebf(float x) {
    unsigned u = __float_as_uint(x);
    return (ushort)((u + 0x7fffu + ((u >> 16) & 1u)) >> 16);
}

// ---- X [8192][512] fp32 -> Xh/Xl [z][8192][512] bf16 planes (row-major, no transpose) ----
__global__ __launch_bounds__(256) void xsplit3_kernel(
    const float* __restrict__ X0, const float* __restrict__ X1, const float* __restrict__ X2,
    ushort* __restrict__ Xh, ushort* __restrict__ Xl)
{
    const int z = blockIdx.z;
    const float* X = (z == 0) ? X0 : (z == 1) ? X1 : X2;
    const size_t base = (size_t)blockIdx.x * 2048 + (size_t)threadIdx.x * 8;
    float4 a = *(const float4*)(X + base);
    float4 b = *(const float4*)(X + base + 4);
    float v[8] = {a.x, a.y, a.z, a.w, b.x, b.y, b.z, b.w};
    ushort hs[8], ls[8];
    #pragma unroll
    for (int j = 0; j < 8; ++j) splitbf(v[j], hs[j], ls[j]);
    uint4 wh, wl;
    wh.x = hs[0] | ((unsigned)hs[1] << 16); wh.y = hs[2] | ((unsigned)hs[3] << 16);
    wh.z = hs[4] | ((unsigned)hs[5] << 16); wh.w = hs[6] | ((unsigned)hs[7] << 16);
    wl.x = ls[0] | ((unsigned)ls[1] << 16); wl.y = ls[2] | ((unsigned)ls[3] << 16);
    wl.z = ls[4] | ((unsigned)ls[5] << 16); wl.w = ls[6] | ((unsigned)ls[7] << 16);
    size_t off = (size_t)z * 8192 * 512 + base;
    *(uint4*)(Xh + off) = wh;
    *(uint4*)(Xl + off) = wl;
}

// ---- W [512k][512n] fp32 -> WT [z*512 + n][k] bf16 hi/lo planes ----
__global__ __launch_bounds__(256) void wsplit3_kernel(
    const float* __restrict__ W0, const float* __restrict__ W1, const float* __restrict__ W2,
    ushort* __restrict__ WTh, ushort* __restrict__ WTl)
{
    __shared__ float T[64][65];
    const int z = blockIdx.z;
    const float* W = (z == 0) ? W0 : (z == 1) ? W1 : W2;
    const int k0 = blockIdx.x * 64, n0 = blockIdx.y * 64;
    const int tid = threadIdx.x;
    #pragma unroll
    for (int i = 0; i < 4; ++i) {
        int u = tid + i * 256;
        int row = u >> 4, c4 = (u & 15) * 4;
        float4 v = *(const float4*)(W + (size_t)(k0 + row) * 512 + n0 + c4);
        T[row][c4 + 0] = v.x; T[row][c4 + 1] = v.y; T[row][c4 + 2] = v.z; T[row][c4 + 3] = v.w;
    }
    __syncthreads();
    #pragma unroll
    for (int i = 0; i < 2; ++i) {
        int u = tid + i * 256;
        int d = u >> 3, c8 = (u & 7) * 8;
        ushort hs[8], ls[8];
        #pragma unroll
        for (int j = 0; j < 8; ++j) splitbf(T[c8 + j][d], hs[j], ls[j]);
        uint4 wh, wl;
        wh.x = hs[0] | ((unsigned)hs[1] << 16); wh.y = hs[2] | ((unsigned)hs[3] << 16);
        wh.z = hs[4] | ((unsigned)hs[5] << 16); wh.w = hs[6] | ((unsigned)hs[7] << 16);
        wl.x = ls[0] | ((unsigned)ls[1] << 16); wl.y = ls[2] | ((unsigned)ls[3] << 16);
        wl.z = ls[4] | ((unsigned)ls[5] << 16); wl.w = ls[6] | ((unsigned)ls[7] << 16);
        size_t off = (size_t)(z * 512 + n0 + d) * 512 + k0 + c8;
        *(uint4*)(WTh + off) = wh;
        *(uint4*)(WTl + off) = wl;
    }
}

// ---- GEMM2: 128x64 tile, BK=32, 4 waves (64x32 each), dbuf FULLY-async staging ----
// A now staged via global_load_lds from pre-split bf16 planes (no fp32 load, no
// splitbf, no register round-trip). LDS 48KB -> 3 blocks/CU. Numerics identical
// (planes hold the same splitbf values the old in-register path produced).
// final_=0: mi = y>>3 selects plane subregion 0/1/2 -> Q/K/V outputs
// final_=1: fp32 out to Cf
union GS {
    struct {
        ushort Ah[2][128 * 32];
        ushort Al[2][128 * 32];
        ushort Bh[2][2048];
        ushort Bl[2][2048];
    } s;
    ushort E[24576];
};

__global__ __launch_bounds__(256) void gemm2_kernel(
    const ushort* __restrict__ AhP, const ushort* __restrict__ AlP,
    const ushort* __restrict__ BhT, const ushort* __restrict__ BlT,
    const float* __restrict__ b0, const float* __restrict__ b1, const float* __restrict__ b2,
    int final_, float* __restrict__ Cf,
    ushort* __restrict__ Qh, ushort* __restrict__ Ql, ushort* __restrict__ Khp,
    ushort* __restrict__ VhT, ushort* __restrict__ VlT)
{
    __shared__ __align__(16) GS gs;
    const int tid = threadIdx.x;
    const int wave = tid >> 6, lane = tid & 63;
    const int l15 = lane & 15, quad = lane >> 4;
    const int m0 = blockIdx.x * 128;
    const int yy = blockIdx.y;
    const int mi = yy >> 3, n0 = (yy & 7) * 64;
    const int nglob = mi * 512 + n0;
    const float* bias = (mi == 0) ? b0 : (mi == 1) ? b1 : b2;
    const int wm = (wave & 1) * 64, wn = (wave >> 1) * 32;

    // A async staging: 4 regions/wave (ri = wave*4+j; plane ri>>3, rowblock ri&7)
    // lane l covers row rb*16+(l>>2), chunk l&3; src chunk XOR-swizzled by (row>>1)&3
    const ushort* AhZ = AhP + (size_t)mi * 8192 * 512;
    const ushort* AlZ = AlP + (size_t)mi * 8192 * 512;
    const int arow = lane >> 2;
    const int acsw = ((lane & 3) ^ ((lane >> 3) & 3)) * 8;
    const ushort* asrc[4]; int adst[4], apl[4];
    #pragma unroll
    for (int j = 0; j < 4; ++j) {
        int ri = wave * 4 + j, pl = ri >> 3, rb = ri & 7;
        asrc[j] = (pl ? AlZ : AhZ) + (size_t)(m0 + rb * 16 + arow) * 512 + acsw;
        adst[j] = rb * 512 + lane * 8;   // ushort idx; = uniform + lane*16B
        apl[j] = pl;
    }
    // B staging (async): wave stages rows wave*16..+15 of both planes, XOR-swizzled
    const int brow = lane >> 2, bsrc = (lane & 3) ^ (brow & 3);
    const ushort* bhp = BhT + (size_t)(nglob + wave * 16 + brow) * 512 + bsrc * 8;
    const ushort* blp = BlT + (size_t)(nglob + wave * 16 + brow) * 512 + bsrc * 8;
    const int bdst = wave * 512 + lane * 8;

    f32x4 acc[4][2];
    #pragma unroll
    for (int i = 0; i < 4; ++i)
        #pragma unroll
        for (int j = 0; j < 2; ++j) acc[i][j] = (f32x4){0.f, 0.f, 0.f, 0.f};

    // prologue: stage t=0
    #pragma unroll
    for (int j = 0; j < 4; ++j)
        async16(asrc[j], apl[j] ? &gs.s.Al[0][adst[j]] : &gs.s.Ah[0][adst[j]]);
    async16(bhp, &gs.s.Bh[0][bdst]);
    async16(blp, &gs.s.Bl[0][bdst]);

    for (int t = 0; t < 16; ++t) {
        const int p = t & 1;
        __syncthreads();   // drains async(t); all reads of buf 1-p done
        if (t < 15) {
            const int kn = (t + 1) * 32;
            #pragma unroll
            for (int j = 0; j < 4; ++j)
                async16(asrc[j] + kn, apl[j] ? &gs.s.Al[1 - p][adst[j]] : &gs.s.Ah[1 - p][adst[j]]);
            async16(bhp + kn, &gs.s.Bh[1 - p][bdst]);
            async16(blp + kn, &gs.s.Bl[1 - p][bdst]);
        }
        bf16x8 afh[4], afl[4];
        #pragma unroll
        for (int ms = 0; ms < 4; ++ms) {
            int off = (wm + ms * 16 + l15) * 32 + (quad ^ ((l15 >> 1) & 3)) * 8;
            afh[ms] = *(const bf16x8*)&gs.s.Ah[p][off];
            afl[ms] = *(const bf16x8*)&gs.s.Al[p][off];
        }
        #pragma unroll
        for (int ns = 0; ns < 2; ++ns) {
            int off = (wn + ns * 16 + l15) * 32 + (quad ^ (l15 & 3)) * 8;
            bf16x8 bfh = *(const bf16x8*)&gs.s.Bh[p][off];
            bf16x8 bfl = *(const bf16x8*)&gs.s.Bl[p][off];
            #pragma unroll
            for (int ms = 0; ms < 4; ++ms) {
                acc[ms][ns] = MFMA16(afh[ms], bfl, acc[ms][ns]);
                acc[ms][ns] = MFMA16(afl[ms], bfh, acc[ms][ns]);
                acc[ms][ns] = MFMA16(afh[ms], bfh, acc[ms][ns]);
            }
        }
    }

    // bias
    #pragma unroll
    for (int ns = 0; ns < 2; ++ns) {
        float bv = bias[n0 + wn + ns * 16 + l15];
        #pragma unroll
        for (int ms = 0; ms < 4; ++ms)
            #pragma unroll
            for (int r = 0; r < 4; ++r) acc[ms][ns][r] += bv;
    }

    if (final_) {   // coalesced fp32 stores (16 lanes x 4B = 64B lines)
        #pragma unroll
        for (int ns = 0; ns < 2; ++ns) {
            int col = n0 + wn + ns * 16 + l15;
            #pragma unroll
            for (int ms = 0; ms < 4; ++ms)
                #pragma unroll
                for (int r = 0; r < 4; ++r)
                    Cf[(size_t)(m0 + wm + ms * 16 + quad * 4 + r) * 512 + col] = acc[ms][ns][r];
        }
        return;
    }

    const int h0 = n0 >> 6;
    const int b = m0 >> 11, rr0 = m0 & 2047;
    const int passes = (mi == 1) ? 1 : 2;
    for (int pass = 0; pass < passes; ++pass) {
        __syncthreads();
        // acc -> LDS (V: transposed [col][row], b64; Q/K: row-major [row][col], b16)
        #pragma unroll
        for (int ms = 0; ms < 4; ++ms) {
            #pragma unroll
            for (int ns = 0; ns < 2; ++ns) {
                int cl = wn + ns * 16 + l15;
                int rl = wm + ms * 16 + quad * 4;
                if (mi == 2) {
                    ushort4 w4;
                    #pragma unroll
                    for (int r = 0; r < 4; ++r) {
                        ushort h, l; splitbf(acc[ms][ns][r], h, l);
                        ((ushort*)&w4)[r] = pass ? l : h;
                    }
                    *(ushort4*)&gs.E[cl * 136 + rl] = w4;
                } else {
                    #pragma unroll
                    for (int r = 0; r < 4; ++r) {
                        float v = acc[ms][ns][r];
                        ushort out;
                        if (mi == 1) out = rnebf(v);
                        else { ushort h, l; splitbf(v, h, l); out = pass ? l : h; }
                        gs.E[(rl + r) * 72 + cl] = out;
                    }
                }
            }
        }
        __syncthreads();
        // LDS -> global, wide coalesced uint4
        if (mi == 2) {
            ushort* dst = pass ? VlT : VhT;
            #pragma unroll
            for (int i = 0; i < 4; ++i) {
                int idx = tid + i * 256;
                int d = idx >> 4, rg = idx & 15;
                uint4 u = *(const uint4*)&gs.E[d * 136 + rg * 8];
                *(uint4*)&dst[((size_t)(b * 8 + h0) * 64 + d) * 2048 + rr0 + rg * 8] = u;
            }
        } else {
            ushort* dst = (mi == 0) ? (pass ? Ql : Qh) : Khp;
            #pragma unroll
            for (int i = 0; i < 4; ++i) {
                int idx = tid + i * 256;
                int row = idx >> 3, cg = idx & 7;
                uint4 u = *(const uint4*)&gs.E[row * 72 + cg * 8];
                *(uint4*)&dst[((size_t)(b * 8 + h0) * 2048 + rr0 + row) * 64 + cg * 8] = u;
            }
        }
    }
}

// ---- Flash attention (r7 structure, fast softmax; epilogue writes bf16 planes) ----
// S^T dataflow, in-block split-K, async dbuf, 512 threads, 16 barriers.
// Epilogue: splitbf the fp32 output into XSh/XSl planes (bit-identical to what
// the out-proj GEMM used to compute from fp32 XS) so the final GEMM can stage
// A asynchronously too.
union SmemU {
    struct { ushort KVs[2][6][4096]; ushort Pp[8][64 * LDP6]; } p1;
    struct { float Obuf[4][64 * 68]; float Lbuf[4][64]; } p2;
};

__global__ __launch_bounds__(512, 2) void attn3_kernel(
    const ushort* __restrict__ Qh, const ushort* __restrict__ Ql,
    const ushort* __restrict__ Kh, const ushort* __restrict__ VhT,
    const ushort* __restrict__ VlT, const int* __restrict__ mask,
    ushort* __restrict__ XSh, ushort* __restrict__ XSl)
{
    __shared__ SmemU smem;
    const int tid = threadIdx.x;
    const int wave = tid >> 6, lane = tid & 63;
    const int l15 = lane & 15, quad = lane >> 4;
    const int w4 = wave & 3, half = wave >> 2;
    const int bh = blockIdx.x, b = bh >> 3, h = bh & 7;
    const int q0 = blockIdx.y * 256;

    bf16x8 qh[4][2], ql[4][2];
    #pragma unroll
    for (int qs = 0; qs < 4; ++qs) {
        size_t qb = ((size_t)bh * 2048 + q0 + w4 * 64 + qs * 16 + l15) * 64 + quad * 8;
        qh[qs][0] = *(const bf16x8*)(Qh + qb);
        qh[qs][1] = *(const bf16x8*)(Qh + qb + 32);
        ql[qs][0] = *(const bf16x8*)(Ql + qb);
        ql[qs][1] = *(const bf16x8*)(Ql + qb + 32);
    }

    const f32x4 z = {0.f, 0.f, 0.f, 0.f};
    f32x4 oacc[4][4];
    #pragma unroll
    for (int i = 0; i < 4; ++i)
        #pragma unroll
        for (int j = 0; j < 4; ++j) oacc[i][j] = z;
    float lacc[4] = {0.f, 0.f, 0.f, 0.f};

    const int rloc = lane >> 3, gsw = (lane & 7) ^ rloc;
    const ushort* sb[6]; size_t sstep[6]; int dofs[6];
    #pragma unroll
    for (int i = 0; i < 6; ++i) {
        int cc = wave * 6 + i;
        int hc = cc / 24, r24 = cc % 24, pc = r24 >> 3, ic = r24 & 7;
        if (pc == 0) {
            sb[i] = Kh + ((size_t)(bh * 2048 + hc * 1024 + ic * 8 + rloc)) * 64 + gsw * 8;
            sstep[i] = (size_t)64 * 64;
        } else {
            const ushort* vp = (pc == 1) ? VhT : VlT;
            sb[i] = vp + ((size_t)(bh * 64 + ic * 8 + rloc)) * 2048 + hc * 1024 + gsw * 8;
            sstep[i] = 64;
        }
        dofs[i] = (hc * 3 + pc) * 4096 + ic * 512;
    }

    const int sw0 = (quad ^ (l15 & 7)) * 8;
    const int mrow0 = b * 2048 + half * 1024;
    const float SCL = 0.18033688011112042f;   // 0.125 * log2(e)

    #pragma unroll
    for (int i = 0; i < 6; ++i)
        async16(sb[i], &smem.p1.KVs[0][0][0] + dofs[i]);

    for (int t = 0; t < 16; ++t) {
        __syncthreads();
        if (t < 15) {
            #pragma unroll
            for (int i = 0; i < 6; ++i)
                async16(sb[i] + (size_t)(t + 1) * sstep[i], &smem.p1.KVs[(t + 1) & 1][0][0] + dofs[i]);
        }
        const int p = t & 1;
        const ushort* K0 = smem.p1.KVs[p][half * 3 + 0];
        const ushort* V0 = smem.p1.KVs[p][half * 3 + 1];
        const ushort* V1 = smem.p1.KVs[p][half * 3 + 2];
        ushort* Pw = smem.p1.Pp[wave];

        #pragma unroll
        for (int ks = 0; ks < 2; ++ks) {
            #pragma unroll
            for (int kt2 = 0; kt2 < 2; ++kt2) {
                const int kt = ks * 2 + kt2;
                const int kb = (kt * 16 + l15) * 64;
                bf16x8 ka0 = *(const bf16x8*)&K0[kb + sw0];
                bf16x8 ka1 = *(const bf16x8*)&K0[kb + (sw0 ^ 32)];
                int4 mv = *(const int4*)(mask + mrow0 + t * 64 + kt * 16 + quad * 4);
                float bias[4];   // log2-domain mask bias
                bias[0] = mv.x ? 0.f : -1e38f; bias[1] = mv.y ? 0.f : -1e38f;
                bias[2] = mv.z ? 0.f : -1e38f; bias[3] = mv.w ? 0.f : -1e38f;
                #pragma unroll
                for (int qs = 0; qs < 4; ++qs) {
                    f32x4 a = z;
                    a = MFMA16(ka0, ql[qs][0], a);
                    a = MFMA16(ka1, ql[qs][1], a);
                    a = MFMA16(ka0, qh[qs][0], a);
                    a = MFMA16(ka1, qh[qs][1], a);
                    float pv[4];
                    #pragma unroll
                    for (int r = 0; r < 4; ++r) {
                        float x = __builtin_fmaf(a[r], SCL, bias[r]);
                        float e; asm("v_exp_f32 %0, %1" : "=v"(e) : "v"(x));
                        lacc[qs] += e;
                        pv[r] = e;
                    }
                    unsigned u01, u23;
                    asm("v_cvt_pk_bf16_f32 %0, %1, %2" : "=v"(u01) : "v"(pv[0]), "v"(pv[1]));
                    asm("v_cvt_pk_bf16_f32 %0, %1, %2" : "=v"(u23) : "v"(pv[2]), "v"(pv[3]));
                    uint2 w2; w2.x = u01; w2.y = u23;
                    *(uint2*)&Pw[(qs * 16 + l15) * LDP6 + kt2 * 16 + quad * 4] = w2;
                }
            }
            const int svo = sw0 ^ (ks * 32);
            bf16x8 pf[4];
            #pragma unroll
            for (int qs = 0; qs < 4; ++qs)
                pf[qs] = *(const bf16x8*)&Pw[(qs * 16 + l15) * LDP6 + quad * 8];
            #pragma unroll
            for (int dsub = 0; dsub < 4; ++dsub) {
                const int vb = (dsub * 16 + l15) * 64;
                bf16x8 vh = *(const bf16x8*)&V0[vb + svo];
                bf16x8 vl = *(const bf16x8*)&V1[vb + svo];
                #pragma unroll
                for (int qs = 0; qs < 4; ++qs) {
                    oacc[qs][dsub] = MFMA16(vl, pf[qs], oacc[qs][dsub]);
                    oacc[qs][dsub] = MFMA16(vh, pf[qs], oacc[qs][dsub]);
                }
            }
        }
    }

    float lv[4];
    #pragma unroll
    for (int qs = 0; qs < 4; ++qs) {
        float v = lacc[qs];
        v += __shfl_xor(v, 16);
        v += __shfl_xor(v, 32);
        lv[qs] = v;
    }

    __syncthreads();
    if (half == 1) {
        #pragma unroll
        for (int qs = 0; qs < 4; ++qs) {
            #pragma unroll
            for (int dsub = 0; dsub < 4; ++dsub) {
                float4 o4 = {oacc[qs][dsub][0], oacc[qs][dsub][1], oacc[qs][dsub][2], oacc[qs][dsub][3]};
                *(float4*)&smem.p2.Obuf[w4][(qs * 16 + l15) * 68 + dsub * 16 + quad * 4] = o4;
            }
            if (quad == 0) smem.p2.Lbuf[w4][qs * 16 + l15] = lv[qs];
        }
    }
    __syncthreads();
    if (half == 0) {
        #pragma unroll
        for (int qs = 0; qs < 4; ++qs) {
            float ltot = lv[qs] + smem.p2.Lbuf[w4][qs * 16 + l15];
            float inv = (ltot > 0.f) ? 1.f / ltot : 0.f;
            int row = q0 + w4 * 64 + qs * 16 + l15;
            ushort* rph = XSh + ((size_t)(b * 2048 + row)) * 512 + h * 64;
            ushort* rpl = XSl + ((size_t)(b * 2048 + row)) * 512 + h * 64;
            #pragma unroll
            for (int dsub = 0; dsub < 4; ++dsub) {
                float4 p4 = *(const float4*)&smem.p2.Obuf[w4][(qs * 16 + l15) * 68 + dsub * 16 + quad * 4];
                float s0 = (oacc[qs][dsub][0] + p4.x) * inv;
                float s1 = (oacc[qs][dsub][1] + p4.y) * inv;
                float s2 = (oacc[qs][dsub][2] + p4.z) * inv;
                float s3 = (oacc[qs][dsub][3] + p4.w) * inv;
                ushort4 hv, lv4;
                splitbf(s0, hv.x, lv4.x); splitbf(s1, hv.y, lv4.y);
                splitbf(s2, hv.z, lv4.z); splitbf(s3, hv.w, lv4.w);
                *(ushort4*)&rph[dsub * 16 + quad * 4] = hv;
                *(ushort4*)&rpl[dsub * 16 + quad * 4] = lv4;
            }
        }
    }
}

extern "C" void kernel_launch(void* const* d_in, const int* in_sizes, int n_in,
                              void* d_out, int out_size, void* d_ws, size_t ws_size,
                              hipStream_t stream) {
    const float* query = (const float*)d_in[0];
    const float* key   = (const float*)d_in[1];
    const float* value = (const float*)d_in[2];
    const int*   mask  = (const int*)d_in[3];
    const float* Wq = (const float*)d_in[4];
    const float* bq = (const float*)d_in[5];
    const float* Wk = (const float*)d_in[6];
    const float* bk = (const float*)d_in[7];
    const float* Wv = (const float*)d_in[8];
    const float* bv = (const float*)d_in[9];
    const float* Wo = (const float*)d_in[10];
    const float* bo = (const float*)d_in[11];

    char* w = (char*)d_ws;
    const size_t MB = (size_t)1 << 20;
    ushort* Qh  = (ushort*)(w + 0 * MB);
    ushort* Ql  = (ushort*)(w + 8 * MB);
    ushort* Khp = (ushort*)(w + 16 * MB);
    ushort* VhT = (ushort*)(w + 24 * MB);
    ushort* VlT = (ushort*)(w + 32 * MB);
    ushort* Xh3 = (ushort*)(w + 40 * MB);   // [3][8192][512], 24MB, dead after gemm#1
    ushort* Xl3 = (ushort*)(w + 64 * MB);   // 24MB, dead after gemm#1
    ushort* XSh = (ushort*)(w + 56 * MB);   // 8MB, overlays Xh3 tail (temporally disjoint)
    ushort* XSl = (ushort*)(w + 64 * MB);   // 8MB, overlays Xl3 head (temporally disjoint)
    ushort* WTh = (ushort*)(w + 88 * MB);   // [1536][512]
    ushort* WTl = WTh + (size_t)1536 * 512;
    // Wo planes reuse the Qh region (dead after attn3)
    ushort* WoTh = (ushort*)(w + 0 * MB);
    ushort* WoTl = WoTh + (size_t)512 * 512;

    xsplit3_kernel<<<dim3(2048, 1, 3), 256, 0, stream>>>(query, key, value, Xh3, Xl3);
    wsplit3_kernel<<<dim3(8, 8, 3), 256, 0, stream>>>(Wq, Wk, Wv, WTh, WTl);
    gemm2_kernel<<<dim3(64, 24), 256, 0, stream>>>(
        Xh3, Xl3, WTh, WTl, bq, bk, bv, 0, nullptr, Qh, Ql, Khp, VhT, VlT);
    attn3_kernel<<<dim3(32, 8), 512, 0, stream>>>(Qh, Ql, Khp, VhT, VlT, mask, XSh, XSl);
    wsplit3_kernel<<<dim3(8, 8, 1), 256, 0, stream>>>(Wo, Wo, Wo, WoTh, WoTl);
    gemm2_kernel<<<dim3(64, 8), 256, 0, stream>>>(
        XSh, XSl, WoTh, WoTl, bo, bo, bo, 1, (float*)d_out,
        nullptr, nullptr, nullptr, nullptr, nullptr);
}

// Round 9
// 241.729 us; speedup vs baseline: 1.2414x; 1.1585x over previous
//
#include <hip/hip_runtime.h>
#include <math.h>

#define Bq 4
#define Lq 2048
#define NH 8
#define LDP6 36   // attn Pp row stride (ushorts): 72B = 18 banks, gcd(18,32)=2 -> conflict-free (r3-verified)

typedef __attribute__((ext_vector_type(8))) __bf16 bf16x8;
typedef __attribute__((ext_vector_type(4))) float f32x4;
#define MFMA16(a,b,c) __builtin_amdgcn_mfma_f32_16x16x32_bf16(a,b,c,0,0,0)

__device__ __forceinline__ void async16(const void* g, void* l) {
    __builtin_amdgcn_global_load_lds(
        (const __attribute__((address_space(1))) unsigned int*)g,
        (__attribute__((address_space(3))) unsigned int*)l, 16, 0, 0);
}

// truncation split: x = hi + lo (+ ~2^-16 rel residual)
__device__ __forceinline__ void splitbf(float x, ushort& h, ushort& l) {
    unsigned u = __float_as_uint(x);
    h = (ushort)(u >> 16);
    float hf = __uint_as_float(u & 0xffff0000u);
    l = (ushort)(__float_as_uint(x - hf) >> 16);
}
// round-to-nearest-even bf16
__device__ __forceinline__ ushort rnebf(float x) {
    unsigned u = __float_as_uint(x);
    return (ushort)((u + 0x7fffu + ((u >> 16) & 1u)) >> 16);
}

// ---- per-batch mask compaction: idx[b][j] = j-th valid key position, nvalid[b] ----
__global__ __launch_bounds__(256) void maskscan_kernel(
    const int* __restrict__ mask, int* __restrict__ idx, int* __restrict__ nvalid)
{
    __shared__ int ss[256];
    const int b = blockIdx.x, tid = threadIdx.x;
    int m[8], s = 0;
    #pragma unroll
    for (int j = 0; j < 8; ++j) { m[j] = (mask[b * 2048 + tid * 8 + j] != 0); s += m[j]; }
    int v = s;
    ss[tid] = v;
    __syncthreads();
    for (int off = 1; off < 256; off <<= 1) {
        int t_ = (tid >= off) ? ss[tid - off] : 0;
        __syncthreads();
        v += t_;
        ss[tid] = v;
        __syncthreads();
    }
    int pos = v - s;   // exclusive prefix
    #pragma unroll
    for (int j = 0; j < 8; ++j) if (m[j]) idx[b * 2048 + pos++] = tid * 8 + j;
    int tot = ss[255];
    if (tid == 0) nvalid[b] = tot;
    for (int k = tot + tid; k < 2048; k += 256) idx[b * 2048 + k] = 0;   // pad -> row 0 (finite)
}

// ---- X [8192][512] fp32 -> Xh/Xl [z][8192][512] bf16 planes ----
// z=0 (query): direct. z=1,2 (key,value): rows GATHERED through idx (compaction).
__global__ __launch_bounds__(256) void xsplit3_kernel(
    const float* __restrict__ X0, const float* __restrict__ X1, const float* __restrict__ X2,
    const int* __restrict__ idx,
    ushort* __restrict__ Xh, ushort* __restrict__ Xl)
{
    const int z = blockIdx.z;
    const float* X = (z == 0) ? X0 : (z == 1) ? X1 : X2;
    const size_t ebase = (size_t)blockIdx.x * 2048 + (size_t)threadIdx.x * 8;
    const int row = (int)(ebase >> 9), col = (int)(ebase & 511);
    const int b = row >> 11, r = row & 2047;
    const int srow = (z == 0) ? row : (b * 2048 + idx[b * 2048 + r]);
    const float* src = X + (size_t)srow * 512 + col;
    float4 a = *(const float4*)(src);
    float4 bb = *(const float4*)(src + 4);
    float vv[8] = {a.x, a.y, a.z, a.w, bb.x, bb.y, bb.z, bb.w};
    ushort hs[8], ls[8];
    #pragma unroll
    for (int j = 0; j < 8; ++j) splitbf(vv[j], hs[j], ls[j]);
    uint4 wh, wl;
    wh.x = hs[0] | ((unsigned)hs[1] << 16); wh.y = hs[2] | ((unsigned)hs[3] << 16);
    wh.z = hs[4] | ((unsigned)hs[5] << 16); wh.w = hs[6] | ((unsigned)hs[7] << 16);
    wl.x = ls[0] | ((unsigned)ls[1] << 16); wl.y = ls[2] | ((unsigned)ls[3] << 16);
    wl.z = ls[4] | ((unsigned)ls[5] << 16); wl.w = ls[6] | ((unsigned)ls[7] << 16);
    size_t off = (size_t)z * 8192 * 512 + ebase;
    *(uint4*)(Xh + off) = wh;
    *(uint4*)(Xl + off) = wl;
}

// ---- W [512k][512n] fp32 -> WT [z*512 + n][k] bf16 hi/lo planes ----
__global__ __launch_bounds__(256) void wsplit3_kernel(
    const float* __restrict__ W0, const float* __restrict__ W1, const float* __restrict__ W2,
    ushort* __restrict__ WTh, ushort* __restrict__ WTl)
{
    __shared__ float T[64][65];
    const int z = blockIdx.z;
    const float* W = (z == 0) ? W0 : (z == 1) ? W1 : W2;
    const int k0 = blockIdx.x * 64, n0 = blockIdx.y * 64;
    const int tid = threadIdx.x;
    #pragma unroll
    for (int i = 0; i < 4; ++i) {
        int u = tid + i * 256;
        int row = u >> 4, c4 = (u & 15) * 4;
        float4 v = *(const float4*)(W + (size_t)(k0 + row) * 512 + n0 + c4);
        T[row][c4 + 0] = v.x; T[row][c4 + 1] = v.y; T[row][c4 + 2] = v.z; T[row][c4 + 3] = v.w;
    }
    __syncthreads();
    #pragma unroll
    for (int i = 0; i < 2; ++i) {
        int u = tid + i * 256;
        int d = u >> 3, c8 = (u & 7) * 8;
        ushort hs[8], ls[8];
        #pragma unroll
        for (int j = 0; j < 8; ++j) splitbf(T[c8 + j][d], hs[j], ls[j]);
        uint4 wh, wl;
        wh.x = hs[0] | ((unsigned)hs[1] << 16); wh.y = hs[2] | ((unsigned)hs[3] << 16);
        wh.z = hs[4] | ((unsigned)hs[5] << 16); wh.w = hs[6] | ((unsigned)hs[7] << 16);
        wl.x = ls[0] | ((unsigned)ls[1] << 16); wl.y = ls[2] | ((unsigned)ls[3] << 16);
        wl.z = ls[4] | ((unsigned)ls[5] << 16); wl.w = ls[6] | ((unsigned)ls[7] << 16);
        size_t off = (size_t)(z * 512 + n0 + d) * 512 + k0 + c8;
        *(uint4*)(WTh + off) = wh;
        *(uint4*)(WTl + off) = wl;
    }
}

// ---- GEMM2: 128x64 tile, BK=32, 4 waves, dbuf fully-async staging ----
// K/V blocks (mi>=1) early-exit beyond ceil128(nvalid[b]) - compacted rows only.
union GS {
    struct {
        ushort Ah[2][128 * 32];
        ushort Al[2][128 * 32];
        ushort Bh[2][2048];
        ushort Bl[2][2048];
    } s;
    ushort E[24576];
};

__global__ __launch_bounds__(256) void gemm2_kernel(
    const ushort* __restrict__ AhP, const ushort* __restrict__ AlP,
    const ushort* __restrict__ BhT, const ushort* __restrict__ BlT,
    const float* __restrict__ b0, const float* __restrict__ b1, const float* __restrict__ b2,
    const int* __restrict__ nvalid, int final_, float* __restrict__ Cf,
    ushort* __restrict__ Qh, ushort* __restrict__ Ql, ushort* __restrict__ Khp,
    ushort* __restrict__ VhT, ushort* __restrict__ VlT)
{
    __shared__ __align__(16) GS gs;
    const int tid = threadIdx.x;
    const int wave = tid >> 6, lane = tid & 63;
    const int l15 = lane & 15, quad = lane >> 4;
    const int m0 = blockIdx.x * 128;
    const int yy = blockIdx.y;
    const int mi = yy >> 3, n0 = (yy & 7) * 64;
    const int nglob = mi * 512 + n0;

    if (!final_ && mi >= 1) {   // uniform early-exit: compacted K/V rows only
        int nv = nvalid[m0 >> 11];
        int nvpad = ((nv + 127) >> 7) << 7;
        if ((m0 & 2047) >= nvpad) return;
    }

    const float* bias = (mi == 0) ? b0 : (mi == 1) ? b1 : b2;
    const int wm = (wave & 1) * 64, wn = (wave >> 1) * 32;

    const ushort* AhZ = AhP + (size_t)mi * 8192 * 512;
    const ushort* AlZ = AlP + (size_t)mi * 8192 * 512;
    const int arow = lane >> 2;
    const int acsw = ((lane & 3) ^ ((lane >> 3) & 3)) * 8;
    const ushort* asrc[4]; int adst[4], apl[4];
    #pragma unroll
    for (int j = 0; j < 4; ++j) {
        int ri = wave * 4 + j, pl = ri >> 3, rb = ri & 7;
        asrc[j] = (pl ? AlZ : AhZ) + (size_t)(m0 + rb * 16 + arow) * 512 + acsw;
        adst[j] = rb * 512 + lane * 8;
        apl[j] = pl;
    }
    const int brow = lane >> 2, bsrc = (lane & 3) ^ (brow & 3);
    const ushort* bhp = BhT + (size_t)(nglob + wave * 16 + brow) * 512 + bsrc * 8;
    const ushort* blp = BlT + (size_t)(nglob + wave * 16 + brow) * 512 + bsrc * 8;
    const int bdst = wave * 512 + lane * 8;

    f32x4 acc[4][2];
    #pragma unroll
    for (int i = 0; i < 4; ++i)
        #pragma unroll
        for (int j = 0; j < 2; ++j) acc[i][j] = (f32x4){0.f, 0.f, 0.f, 0.f};

    #pragma unroll
    for (int j = 0; j < 4; ++j)
        async16(asrc[j], apl[j] ? &gs.s.Al[0][adst[j]] : &gs.s.Ah[0][adst[j]]);
    async16(bhp, &gs.s.Bh[0][bdst]);
    async16(blp, &gs.s.Bl[0][bdst]);

    for (int t = 0; t < 16; ++t) {
        const int p = t & 1;
        __syncthreads();
        if (t < 15) {
            const int kn = (t + 1) * 32;
            #pragma unroll
            for (int j = 0; j < 4; ++j)
                async16(asrc[j] + kn, apl[j] ? &gs.s.Al[1 - p][adst[j]] : &gs.s.Ah[1 - p][adst[j]]);
            async16(bhp + kn, &gs.s.Bh[1 - p][bdst]);
            async16(blp + kn, &gs.s.Bl[1 - p][bdst]);
        }
        bf16x8 afh[4], afl[4];
        #pragma unroll
        for (int ms = 0; ms < 4; ++ms) {
            int off = (wm + ms * 16 + l15) * 32 + (quad ^ ((l15 >> 1) & 3)) * 8;
            afh[ms] = *(const bf16x8*)&gs.s.Ah[p][off];
            afl[ms] = *(const bf16x8*)&gs.s.Al[p][off];
        }
        #pragma unroll
        for (int ns = 0; ns < 2; ++ns) {
            int off = (wn + ns * 16 + l15) * 32 + (quad ^ (l15 & 3)) * 8;
            bf16x8 bfh = *(const bf16x8*)&gs.s.Bh[p][off];
            bf16x8 bfl = *(const bf16x8*)&gs.s.Bl[p][off];
            #pragma unroll
            for (int ms = 0; ms < 4; ++ms) {
                acc[ms][ns] = MFMA16(afh[ms], bfl, acc[ms][ns]);
                acc[ms][ns] = MFMA16(afl[ms], bfh, acc[ms][ns]);
                acc[ms][ns] = MFMA16(afh[ms], bfh, acc[ms][ns]);
            }
        }
    }

    #pragma unroll
    for (int ns = 0; ns < 2; ++ns) {
        float bv = bias[n0 + wn + ns * 16 + l15];
        #pragma unroll
        for (int ms = 0; ms < 4; ++ms)
            #pragma unroll
            for (int r = 0; r < 4; ++r) acc[ms][ns][r] += bv;
    }

    if (final_) {
        #pragma unroll
        for (int ns = 0; ns < 2; ++ns) {
            int col = n0 + wn + ns * 16 + l15;
            #pragma unroll
            for (int ms = 0; ms < 4; ++ms)
                #pragma unroll
                for (int r = 0; r < 4; ++r)
                    Cf[(size_t)(m0 + wm + ms * 16 + quad * 4 + r) * 512 + col] = acc[ms][ns][r];
        }
        return;
    }

    const int h0 = n0 >> 6;
    const int b = m0 >> 11, rr0 = m0 & 2047;
    const int passes = (mi == 1) ? 1 : 2;
    for (int pass = 0; pass < passes; ++pass) {
        __syncthreads();
        #pragma unroll
        for (int ms = 0; ms < 4; ++ms) {
            #pragma unroll
            for (int ns = 0; ns < 2; ++ns) {
                int cl = wn + ns * 16 + l15;
                int rl = wm + ms * 16 + quad * 4;
                if (mi == 2) {
                    ushort4 w4;
                    #pragma unroll
                    for (int r = 0; r < 4; ++r) {
                        ushort h, l; splitbf(acc[ms][ns][r], h, l);
                        ((ushort*)&w4)[r] = pass ? l : h;
                    }
                    *(ushort4*)&gs.E[cl * 136 + rl] = w4;
                } else {
                    #pragma unroll
                    for (int r = 0; r < 4; ++r) {
                        float v = acc[ms][ns][r];
                        ushort out;
                        if (mi == 1) out = rnebf(v);
                        else { ushort h, l; splitbf(v, h, l); out = pass ? l : h; }
                        gs.E[(rl + r) * 72 + cl] = out;
                    }
                }
            }
        }
        __syncthreads();
        if (mi == 2) {
            ushort* dst = pass ? VlT : VhT;
            #pragma unroll
            for (int i = 0; i < 4; ++i) {
                int idx2 = tid + i * 256;
                int d = idx2 >> 4, rg = idx2 & 15;
                uint4 u = *(const uint4*)&gs.E[d * 136 + rg * 8];
                *(uint4*)&dst[((size_t)(b * 8 + h0) * 64 + d) * 2048 + rr0 + rg * 8] = u;
            }
        } else {
            ushort* dst = (mi == 0) ? (pass ? Ql : Qh) : Khp;
            #pragma unroll
            for (int i = 0; i < 4; ++i) {
                int idx2 = tid + i * 256;
                int row = idx2 >> 3, cg = idx2 & 7;
                uint4 u = *(const uint4*)&gs.E[row * 72 + cg * 8];
                *(uint4*)&dst[((size_t)(b * 8 + h0) * 2048 + rr0 + row) * 64 + cg * 8] = u;
            }
        }
    }
}

// ---- Flash attention over COMPACTED keys ----
// nt = ceil(nvalid/128) tiles per half (E[nt]~9 vs fixed 16). Mask is now the
// register compare (key < nvalid): tail keys get -1e38 bias -> exp -> 0 exactly,
// so padded K/V garbage (finite, gathered from row 0) contributes nothing.
union SmemU {
    struct { ushort KVs[2][6][4096]; ushort Pp[8][64 * LDP6]; } p1;
    struct { float Obuf[4][64 * 68]; float Lbuf[4][64]; } p2;
};

__global__ __launch_bounds__(512, 2) void attn3_kernel(
    const ushort* __restrict__ Qh, const ushort* __restrict__ Ql,
    const ushort* __restrict__ Kh, const ushort* __restrict__ VhT,
    const ushort* __restrict__ VlT, const int* __restrict__ nvalid,
    ushort* __restrict__ XSh, ushort* __restrict__ XSl)
{
    __shared__ SmemU smem;
    const int tid = threadIdx.x;
    const int wave = tid >> 6, lane = tid & 63;
    const int l15 = lane & 15, quad = lane >> 4;
    const int w4 = wave & 3, half = wave >> 2;
    const int bh = blockIdx.x, b = bh >> 3, h = bh & 7;
    const int q0 = blockIdx.y * 256;

    const int nv = nvalid[b];
    const int nt = (nv + 127) >> 7;      // tiles per half
    const int kvofs = half * 64 * nt;    // this wave's compacted-key offset

    bf16x8 qh[4][2], ql[4][2];
    #pragma unroll
    for (int qs = 0; qs < 4; ++qs) {
        size_t qb = ((size_t)bh * 2048 + q0 + w4 * 64 + qs * 16 + l15) * 64 + quad * 8;
        qh[qs][0] = *(const bf16x8*)(Qh + qb);
        qh[qs][1] = *(const bf16x8*)(Qh + qb + 32);
        ql[qs][0] = *(const bf16x8*)(Ql + qb);
        ql[qs][1] = *(const bf16x8*)(Ql + qb + 32);
    }

    const f32x4 z = {0.f, 0.f, 0.f, 0.f};
    f32x4 oacc[4][4];
    #pragma unroll
    for (int i = 0; i < 4; ++i)
        #pragma unroll
        for (int j = 0; j < 4; ++j) oacc[i][j] = z;
    float lacc[4] = {0.f, 0.f, 0.f, 0.f};

    const int rloc = lane >> 3, gsw = (lane & 7) ^ rloc;
    const ushort* sb[6]; size_t sstep[6]; int dofs[6];
    #pragma unroll
    for (int i = 0; i < 6; ++i) {
        int cc = wave * 6 + i;
        int hc = cc / 24, r24 = cc % 24, pc = r24 >> 3, ic = r24 & 7;
        if (pc == 0) {
            sb[i] = Kh + ((size_t)(bh * 2048 + hc * 64 * nt + ic * 8 + rloc)) * 64 + gsw * 8;
            sstep[i] = (size_t)64 * 64;
        } else {
            const ushort* vp = (pc == 1) ? VhT : VlT;
            sb[i] = vp + ((size_t)(bh * 64 + ic * 8 + rloc)) * 2048 + hc * 64 * nt + gsw * 8;
            sstep[i] = 64;
        }
        dofs[i] = (hc * 3 + pc) * 4096 + ic * 512;
    }

    const int sw0 = (quad ^ (l15 & 7)) * 8;
    const float SCL = 0.18033688011112042f;   // 0.125 * log2(e)

    if (nt > 0) {
        #pragma unroll
        for (int i = 0; i < 6; ++i)
            async16(sb[i], &smem.p1.KVs[0][0][0] + dofs[i]);
    }

    for (int t = 0; t < nt; ++t) {
        __syncthreads();
        if (t + 1 < nt) {
            #pragma unroll
            for (int i = 0; i < 6; ++i)
                async16(sb[i] + (size_t)(t + 1) * sstep[i], &smem.p1.KVs[(t + 1) & 1][0][0] + dofs[i]);
        }
        const int p = t & 1;
        const ushort* K0 = smem.p1.KVs[p][half * 3 + 0];
        const ushort* V0 = smem.p1.KVs[p][half * 3 + 1];
        const ushort* V1 = smem.p1.KVs[p][half * 3 + 2];
        ushort* Pw = smem.p1.Pp[wave];

        #pragma unroll
        for (int ks = 0; ks < 2; ++ks) {
            #pragma unroll
            for (int kt2 = 0; kt2 < 2; ++kt2) {
                const int kt = ks * 2 + kt2;
                const int kb = (kt * 16 + l15) * 64;
                bf16x8 ka0 = *(const bf16x8*)&K0[kb + sw0];
                bf16x8 ka1 = *(const bf16x8*)&K0[kb + (sw0 ^ 32)];
                const int kbase = kvofs + t * 64 + kt * 16 + quad * 4;
                float bias[4];   // log2-domain tail bias (replaces mask loads)
                #pragma unroll
                for (int r = 0; r < 4; ++r) bias[r] = (kbase + r < nv) ? 0.f : -1e38f;
                #pragma unroll
                for (int qs = 0; qs < 4; ++qs) {
                    f32x4 a = z;
                    a = MFMA16(ka0, ql[qs][0], a);
                    a = MFMA16(ka1, ql[qs][1], a);
                    a = MFMA16(ka0, qh[qs][0], a);
                    a = MFMA16(ka1, qh[qs][1], a);
                    float pv[4];
                    #pragma unroll
                    for (int r = 0; r < 4; ++r) {
                        float x = __builtin_fmaf(a[r], SCL, bias[r]);
                        float e; asm("v_exp_f32 %0, %1" : "=v"(e) : "v"(x));
                        lacc[qs] += e;
                        pv[r] = e;
                    }
                    unsigned u01, u23;
                    asm("v_cvt_pk_bf16_f32 %0, %1, %2" : "=v"(u01) : "v"(pv[0]), "v"(pv[1]));
                    asm("v_cvt_pk_bf16_f32 %0, %1, %2" : "=v"(u23) : "v"(pv[2]), "v"(pv[3]));
                    uint2 w2; w2.x = u01; w2.y = u23;
                    *(uint2*)&Pw[(qs * 16 + l15) * LDP6 + kt2 * 16 + quad * 4] = w2;
                }
            }
            const int svo = sw0 ^ (ks * 32);
            bf16x8 pf[4];
            #pragma unroll
            for (int qs = 0; qs < 4; ++qs)
                pf[qs] = *(const bf16x8*)&Pw[(qs * 16 + l15) * LDP6 + quad * 8];
            #pragma unroll
            for (int dsub = 0; dsub < 4; ++dsub) {
                const int vb = (dsub * 16 + l15) * 64;
                bf16x8 vh = *(const bf16x8*)&V0[vb + svo];
                bf16x8 vl = *(const bf16x8*)&V1[vb + svo];
                #pragma unroll
                for (int qs = 0; qs < 4; ++qs) {
                    oacc[qs][dsub] = MFMA16(vl, pf[qs], oacc[qs][dsub]);
                    oacc[qs][dsub] = MFMA16(vh, pf[qs], oacc[qs][dsub]);
                }
            }
        }
    }

    float lv[4];
    #pragma unroll
    for (int qs = 0; qs < 4; ++qs) {
        float v = lacc[qs];
        v += __shfl_xor(v, 16);
        v += __shfl_xor(v, 32);
        lv[qs] = v;
    }

    __syncthreads();
    if (half == 1) {
        #pragma unroll
        for (int qs = 0; qs < 4; ++qs) {
            #pragma unroll
            for (int dsub = 0; dsub < 4; ++dsub) {
                float4 o4 = {oacc[qs][dsub][0], oacc[qs][dsub][1], oacc[qs][dsub][2], oacc[qs][dsub][3]};
                *(float4*)&smem.p2.Obuf[w4][(qs * 16 + l15) * 68 + dsub * 16 + quad * 4] = o4;
            }
            if (quad == 0) smem.p2.Lbuf[w4][qs * 16 + l15] = lv[qs];
        }
    }
    __syncthreads();
    if (half == 0) {
        #pragma unroll
        for (int qs = 0; qs < 4; ++qs) {
            float ltot = lv[qs] + smem.p2.Lbuf[w4][qs * 16 + l15];
            float inv = (ltot > 0.f) ? 1.f / ltot : 0.f;
            int row = q0 + w4 * 64 + qs * 16 + l15;
            ushort* rph = XSh + ((size_t)(b * 2048 + row)) * 512 + h * 64;
            ushort* rpl = XSl + ((size_t)(b * 2048 + row)) * 512 + h * 64;
            #pragma unroll
            for (int dsub = 0; dsub < 4; ++dsub) {
                float4 p4 = *(const float4*)&smem.p2.Obuf[w4][(qs * 16 + l15) * 68 + dsub * 16 + quad * 4];
                float s0 = (oacc[qs][dsub][0] + p4.x) * inv;
                float s1 = (oacc[qs][dsub][1] + p4.y) * inv;
                float s2 = (oacc[qs][dsub][2] + p4.z) * inv;
                float s3 = (oacc[qs][dsub][3] + p4.w) * inv;
                ushort4 hv, lv4;
                splitbf(s0, hv.x, lv4.x); splitbf(s1, hv.y, lv4.y);
                splitbf(s2, hv.z, lv4.z); splitbf(s3, hv.w, lv4.w);
                *(ushort4*)&rph[dsub * 16 + quad * 4] = hv;
                *(ushort4*)&rpl[dsub * 16 + quad * 4] = lv4;
            }
        }
    }
}

extern "C" void kernel_launch(void* const* d_in, const int* in_sizes, int n_in,
                              void* d_out, int out_size, void* d_ws, size_t ws_size,
                              hipStream_t stream) {
    const float* query = (const float*)d_in[0];
    const float* key   = (const float*)d_in[1];
    const float* value = (const float*)d_in[2];
    const int*   mask  = (const int*)d_in[3];
    const float* Wq = (const float*)d_in[4];
    const float* bq = (const float*)d_in[5];
    const float* Wk = (const float*)d_in[6];
    const float* bk = (const float*)d_in[7];
    const float* Wv = (const float*)d_in[8];
    const float* bv = (const float*)d_in[9];
    const float* Wo = (const float*)d_in[10];
    const float* bo = (const float*)d_in[11];

    char* w = (char*)d_ws;
    const size_t MB = (size_t)1 << 20;
    ushort* Qh  = (ushort*)(w + 0 * MB);
    ushort* Ql  = (ushort*)(w + 8 * MB);
    ushort* Khp = (ushort*)(w + 16 * MB);
    ushort* VhT = (ushort*)(w + 24 * MB);
    ushort* VlT = (ushort*)(w + 32 * MB);
    ushort* Xh3 = (ushort*)(w + 40 * MB);   // [3][8192][512], 24MB, dead after gemm#1
    ushort* Xl3 = (ushort*)(w + 64 * MB);   // 24MB, dead after gemm#1
    ushort* XSh = (ushort*)(w + 56 * MB);   // 8MB, overlays Xh3 tail (temporally disjoint)
    ushort* XSl = (ushort*)(w + 64 * MB);   // 8MB, overlays Xl3 head (temporally disjoint)
    ushort* WTh = (ushort*)(w + 88 * MB);   // [1536][512]
    ushort* WTl = WTh + (size_t)1536 * 512; // ends at 91 MB
    int* idxbuf = (int*)(w + 91 * MB);      // [4][2048] int, 32 KB
    int* nvbuf  = (int*)(w + 91 * MB + 65536);
    // Wo planes reuse the Qh region (dead after attn3)
    ushort* WoTh = (ushort*)(w + 0 * MB);
    ushort* WoTl = WoTh + (size_t)512 * 512;

    maskscan_kernel<<<dim3(4), 256, 0, stream>>>(mask, idxbuf, nvbuf);
    xsplit3_kernel<<<dim3(2048, 1, 3), 256, 0, stream>>>(query, key, value, idxbuf, Xh3, Xl3);
    wsplit3_kernel<<<dim3(8, 8, 3), 256, 0, stream>>>(Wq, Wk, Wv, WTh, WTl);
    gemm2_kernel<<<dim3(64, 24), 256, 0, stream>>>(
        Xh3, Xl3, WTh, WTl, bq, bk, bv, nvbuf, 0, nullptr, Qh, Ql, Khp, VhT, VlT);
    attn3_kernel<<<dim3(32, 8), 512, 0, stream>>>(Qh, Ql, Khp, VhT, VlT, nvbuf, XSh, XSl);
    wsplit3_kernel<<<dim3(8, 8, 1), 256, 0, stream>>>(Wo, Wo, Wo, WoTh, WoTl);
    gemm2_kernel<<<dim3(64, 8), 256, 0, stream>>>(
        XSh, XSl, WoTh, WoTl, bo, bo, bo, nvbuf, 1, (float*)d_out,
        nullptr, nullptr, nullptr, nullptr, nullptr);
}

// Round 10
// 222.479 us; speedup vs baseline: 1.3488x; 1.0865x over previous
//
#include <hip/hip_runtime.h>
#include <math.h>

#define Bq 4
#define Lq 2048
#define NH 8
#define LDP6 36   // attn Pp row stride (ushorts): 72B = 18 banks, gcd(18,32)=2 -> conflict-free (r3-verified)

typedef __attribute__((ext_vector_type(8))) __bf16 bf16x8;
typedef __attribute__((ext_vector_type(4))) float f32x4;
#define MFMA16(a,b,c) __builtin_amdgcn_mfma_f32_16x16x32_bf16(a,b,c,0,0,0)

__device__ __forceinline__ void async16(const void* g, void* l) {
    __builtin_amdgcn_global_load_lds(
        (const __attribute__((address_space(1))) unsigned int*)g,
        (__attribute__((address_space(3))) unsigned int*)l, 16, 0, 0);
}

// truncation split: x = hi + lo (+ ~2^-16 rel residual)
__device__ __forceinline__ void splitbf(float x, ushort& h, ushort& l) {
    unsigned u = __float_as_uint(x);
    h = (ushort)(u >> 16);
    float hf = __uint_as_float(u & 0xffff0000u);
    l = (ushort)(__float_as_uint(x - hf) >> 16);
}
// round-to-nearest-even bf16
__device__ __forceinline__ ushort rnebf(float x) {
    unsigned u = __float_as_uint(x);
    return (ushort)((u + 0x7fffu + ((u >> 16) & 1u)) >> 16);
}

// ---- per-batch mask compaction: idx[b][j] = j-th valid key position, nvalid[b] ----
__global__ __launch_bounds__(256) void maskscan_kernel(
    const int* __restrict__ mask, int* __restrict__ idx, int* __restrict__ nvalid)
{
    __shared__ int ss[256];
    const int b = blockIdx.x, tid = threadIdx.x;
    int m[8], s = 0;
    #pragma unroll
    for (int j = 0; j < 8; ++j) { m[j] = (mask[b * 2048 + tid * 8 + j] != 0); s += m[j]; }
    int v = s;
    ss[tid] = v;
    __syncthreads();
    for (int off = 1; off < 256; off <<= 1) {
        int t_ = (tid >= off) ? ss[tid - off] : 0;
        __syncthreads();
        v += t_;
        ss[tid] = v;
        __syncthreads();
    }
    int pos = v - s;   // exclusive prefix
    #pragma unroll
    for (int j = 0; j < 8; ++j) if (m[j]) idx[b * 2048 + pos++] = tid * 8 + j;
    int tot = ss[255];
    if (tid == 0) nvalid[b] = tot;
    for (int k = tot + tid; k < 2048; k += 256) idx[b * 2048 + k] = 0;   // pad -> row 0 (finite)
}

// ---- X [8192][512] fp32 -> Xh/Xl [z][8192][512] bf16 planes ----
// z=0 (query): direct. z=1,2 (key,value): rows GATHERED through idx (compaction).
__global__ __launch_bounds__(256) void xsplit3_kernel(
    const float* __restrict__ X0, const float* __restrict__ X1, const float* __restrict__ X2,
    const int* __restrict__ idx,
    ushort* __restrict__ Xh, ushort* __restrict__ Xl)
{
    const int z = blockIdx.z;
    const float* X = (z == 0) ? X0 : (z == 1) ? X1 : X2;
    const size_t ebase = (size_t)blockIdx.x * 2048 + (size_t)threadIdx.x * 8;
    const int row = (int)(ebase >> 9), col = (int)(ebase & 511);
    const int b = row >> 11, r = row & 2047;
    const int srow = (z == 0) ? row : (b * 2048 + idx[b * 2048 + r]);
    const float* src = X + (size_t)srow * 512 + col;
    float4 a = *(const float4*)(src);
    float4 bb = *(const float4*)(src + 4);
    float vv[8] = {a.x, a.y, a.z, a.w, bb.x, bb.y, bb.z, bb.w};
    ushort hs[8], ls[8];
    #pragma unroll
    for (int j = 0; j < 8; ++j) splitbf(vv[j], hs[j], ls[j]);
    uint4 wh, wl;
    wh.x = hs[0] | ((unsigned)hs[1] << 16); wh.y = hs[2] | ((unsigned)hs[3] << 16);
    wh.z = hs[4] | ((unsigned)hs[5] << 16); wh.w = hs[6] | ((unsigned)hs[7] << 16);
    wl.x = ls[0] | ((unsigned)ls[1] << 16); wl.y = ls[2] | ((unsigned)ls[3] << 16);
    wl.z = ls[4] | ((unsigned)ls[5] << 16); wl.w = ls[6] | ((unsigned)ls[7] << 16);
    size_t off = (size_t)z * 8192 * 512 + ebase;
    *(uint4*)(Xh + off) = wh;
    *(uint4*)(Xl + off) = wl;
}

// ---- W [512k][512n] fp32 -> WT [z*512 + n][k] bf16 hi/lo planes (z=0..3: Wq,Wk,Wv,Wo) ----
__global__ __launch_bounds__(256) void wsplit4_kernel(
    const float* __restrict__ W0, const float* __restrict__ W1,
    const float* __restrict__ W2, const float* __restrict__ W3,
    ushort* __restrict__ WTh, ushort* __restrict__ WTl)
{
    __shared__ float T[64][65];
    const int z = blockIdx.z;
    const float* W = (z == 0) ? W0 : (z == 1) ? W1 : (z == 2) ? W2 : W3;
    const int k0 = blockIdx.x * 64, n0 = blockIdx.y * 64;
    const int tid = threadIdx.x;
    #pragma unroll
    for (int i = 0; i < 4; ++i) {
        int u = tid + i * 256;
        int row = u >> 4, c4 = (u & 15) * 4;
        float4 v = *(const float4*)(W + (size_t)(k0 + row) * 512 + n0 + c4);
        T[row][c4 + 0] = v.x; T[row][c4 + 1] = v.y; T[row][c4 + 2] = v.z; T[row][c4 + 3] = v.w;
    }
    __syncthreads();
    #pragma unroll
    for (int i = 0; i < 2; ++i) {
        int u = tid + i * 256;
        int d = u >> 3, c8 = (u & 7) * 8;
        ushort hs[8], ls[8];
        #pragma unroll
        for (int j = 0; j < 8; ++j) splitbf(T[c8 + j][d], hs[j], ls[j]);
        uint4 wh, wl;
        wh.x = hs[0] | ((unsigned)hs[1] << 16); wh.y = hs[2] | ((unsigned)hs[3] << 16);
        wh.z = hs[4] | ((unsigned)hs[5] << 16); wh.w = hs[6] | ((unsigned)hs[7] << 16);
        wl.x = ls[0] | ((unsigned)ls[1] << 16); wl.y = ls[2] | ((unsigned)ls[3] << 16);
        wl.z = ls[4] | ((unsigned)ls[5] << 16); wl.w = ls[6] | ((unsigned)ls[7] << 16);
        size_t off = (size_t)(z * 512 + n0 + d) * 512 + k0 + c8;
        *(uint4*)(WTh + off) = wh;
        *(uint4*)(WTl + off) = wl;
    }
}

// ---- GEMM2: 128x64 tile, BK=32, 4 waves, dbuf fully-async staging ----
// K/V blocks (mi>=1) early-exit beyond ceil128(nvalid[b]). Single-pass RNE-bf16
// epilogue for all of Q/K/V (single-plane outputs; attn drops the lo planes).
union GS {
    struct {
        ushort Ah[2][128 * 32];
        ushort Al[2][128 * 32];
        ushort Bh[2][2048];
        ushort Bl[2][2048];
    } s;
    ushort E[24576];
};

__global__ __launch_bounds__(256) void gemm2_kernel(
    const ushort* __restrict__ AhP, const ushort* __restrict__ AlP,
    const ushort* __restrict__ BhT, const ushort* __restrict__ BlT,
    const float* __restrict__ b0, const float* __restrict__ b1, const float* __restrict__ b2,
    const int* __restrict__ nvalid, int final_, float* __restrict__ Cf,
    ushort* __restrict__ Qh, ushort* __restrict__ Khp, ushort* __restrict__ VhT)
{
    __shared__ __align__(16) GS gs;
    const int tid = threadIdx.x;
    const int wave = tid >> 6, lane = tid & 63;
    const int l15 = lane & 15, quad = lane >> 4;
    const int m0 = blockIdx.x * 128;
    const int yy = blockIdx.y;
    const int mi = yy >> 3, n0 = (yy & 7) * 64;
    const int nglob = mi * 512 + n0;

    if (!final_ && mi >= 1) {   // uniform early-exit: compacted K/V rows only
        int nv = nvalid[m0 >> 11];
        int nvpad = ((nv + 127) >> 7) << 7;
        if ((m0 & 2047) >= nvpad) return;
    }

    const float* bias = (mi == 0) ? b0 : (mi == 1) ? b1 : b2;
    const int wm = (wave & 1) * 64, wn = (wave >> 1) * 32;

    const ushort* AhZ = AhP + (size_t)mi * 8192 * 512;
    const ushort* AlZ = AlP + (size_t)mi * 8192 * 512;
    const int arow = lane >> 2;
    const int acsw = ((lane & 3) ^ ((lane >> 3) & 3)) * 8;
    const ushort* asrc[4]; int adst[4], apl[4];
    #pragma unroll
    for (int j = 0; j < 4; ++j) {
        int ri = wave * 4 + j, pl = ri >> 3, rb = ri & 7;
        asrc[j] = (pl ? AlZ : AhZ) + (size_t)(m0 + rb * 16 + arow) * 512 + acsw;
        adst[j] = rb * 512 + lane * 8;
        apl[j] = pl;
    }
    const int brow = lane >> 2, bsrc = (lane & 3) ^ (brow & 3);
    const ushort* bhp = BhT + (size_t)(nglob + wave * 16 + brow) * 512 + bsrc * 8;
    const ushort* blp = BlT + (size_t)(nglob + wave * 16 + brow) * 512 + bsrc * 8;
    const int bdst = wave * 512 + lane * 8;

    f32x4 acc[4][2];
    #pragma unroll
    for (int i = 0; i < 4; ++i)
        #pragma unroll
        for (int j = 0; j < 2; ++j) acc[i][j] = (f32x4){0.f, 0.f, 0.f, 0.f};

    #pragma unroll
    for (int j = 0; j < 4; ++j)
        async16(asrc[j], apl[j] ? &gs.s.Al[0][adst[j]] : &gs.s.Ah[0][adst[j]]);
    async16(bhp, &gs.s.Bh[0][bdst]);
    async16(blp, &gs.s.Bl[0][bdst]);

    for (int t = 0; t < 16; ++t) {
        const int p = t & 1;
        __syncthreads();
        if (t < 15) {
            const int kn = (t + 1) * 32;
            #pragma unroll
            for (int j = 0; j < 4; ++j)
                async16(asrc[j] + kn, apl[j] ? &gs.s.Al[1 - p][adst[j]] : &gs.s.Ah[1 - p][adst[j]]);
            async16(bhp + kn, &gs.s.Bh[1 - p][bdst]);
            async16(blp + kn, &gs.s.Bl[1 - p][bdst]);
        }
        bf16x8 afh[4], afl[4];
        #pragma unroll
        for (int ms = 0; ms < 4; ++ms) {
            int off = (wm + ms * 16 + l15) * 32 + (quad ^ ((l15 >> 1) & 3)) * 8;
            afh[ms] = *(const bf16x8*)&gs.s.Ah[p][off];
            afl[ms] = *(const bf16x8*)&gs.s.Al[p][off];
        }
        #pragma unroll
        for (int ns = 0; ns < 2; ++ns) {
            int off = (wn + ns * 16 + l15) * 32 + (quad ^ (l15 & 3)) * 8;
            bf16x8 bfh = *(const bf16x8*)&gs.s.Bh[p][off];
            bf16x8 bfl = *(const bf16x8*)&gs.s.Bl[p][off];
            #pragma unroll
            for (int ms = 0; ms < 4; ++ms) {
                acc[ms][ns] = MFMA16(afh[ms], bfl, acc[ms][ns]);
                acc[ms][ns] = MFMA16(afl[ms], bfh, acc[ms][ns]);
                acc[ms][ns] = MFMA16(afh[ms], bfh, acc[ms][ns]);
            }
        }
    }

    #pragma unroll
    for (int ns = 0; ns < 2; ++ns) {
        float bv = bias[n0 + wn + ns * 16 + l15];
        #pragma unroll
        for (int ms = 0; ms < 4; ++ms)
            #pragma unroll
            for (int r = 0; r < 4; ++r) acc[ms][ns][r] += bv;
    }

    if (final_) {
        #pragma unroll
        for (int ns = 0; ns < 2; ++ns) {
            int col = n0 + wn + ns * 16 + l15;
            #pragma unroll
            for (int ms = 0; ms < 4; ++ms)
                #pragma unroll
                for (int r = 0; r < 4; ++r)
                    Cf[(size_t)(m0 + wm + ms * 16 + quad * 4 + r) * 512 + col] = acc[ms][ns][r];
        }
        return;
    }

    const int h0 = n0 >> 6;
    const int b = m0 >> 11, rr0 = m0 & 2047;
    __syncthreads();
    // acc -> LDS, single-pass RNE (V: transposed [col][row]; Q/K: row-major)
    #pragma unroll
    for (int ms = 0; ms < 4; ++ms) {
        #pragma unroll
        for (int ns = 0; ns < 2; ++ns) {
            int cl = wn + ns * 16 + l15;
            int rl = wm + ms * 16 + quad * 4;
            if (mi == 2) {
                ushort4 w4;
                #pragma unroll
                for (int r = 0; r < 4; ++r) ((ushort*)&w4)[r] = rnebf(acc[ms][ns][r]);
                *(ushort4*)&gs.E[cl * 136 + rl] = w4;
            } else {
                #pragma unroll
                for (int r = 0; r < 4; ++r) gs.E[(rl + r) * 72 + cl] = rnebf(acc[ms][ns][r]);
            }
        }
    }
    __syncthreads();
    if (mi == 2) {
        #pragma unroll
        for (int i = 0; i < 4; ++i) {
            int idx2 = tid + i * 256;
            int d = idx2 >> 4, rg = idx2 & 15;
            uint4 u = *(const uint4*)&gs.E[d * 136 + rg * 8];
            *(uint4*)&VhT[((size_t)(b * 8 + h0) * 64 + d) * 2048 + rr0 + rg * 8] = u;
        }
    } else {
        ushort* dst = (mi == 0) ? Qh : Khp;
        #pragma unroll
        for (int i = 0; i < 4; ++i) {
            int idx2 = tid + i * 256;
            int row = idx2 >> 3, cg = idx2 & 7;
            uint4 u = *(const uint4*)&gs.E[row * 72 + cg * 8];
            *(uint4*)&dst[((size_t)(b * 8 + h0) * 2048 + rr0 + row) * 64 + cg * 8] = u;
        }
    }
}

// ---- Flash attention over COMPACTED keys, single-plane Q/K/V ----
// QK^T = q_rne x k_rne (2 MFMA/frag), PV = v_rne x p (1 MFMA/frag):
// 64 MFMA/wave/t (halved vs r9). nt = ceil(nvalid/128) tiles per half.
// Staging per t: K 8K + Vh 8K per half -> KVs[2][4][4096] = 64 KB; LDS 100 KB.
union SmemU {
    struct { ushort KVs[2][4][4096]; ushort Pp[8][64 * LDP6]; } p1;
    struct { float Obuf[4][64 * 68]; float Lbuf[4][64]; } p2;
};

__global__ __launch_bounds__(512, 2) void attn3_kernel(
    const ushort* __restrict__ Qh, const ushort* __restrict__ Kh,
    const ushort* __restrict__ VhT, const int* __restrict__ nvalid,
    ushort* __restrict__ XSh, ushort* __restrict__ XSl)
{
    __shared__ SmemU smem;
    const int tid = threadIdx.x;
    const int wave = tid >> 6, lane = tid & 63;
    const int l15 = lane & 15, quad = lane >> 4;
    const int w4 = wave & 3, half = wave >> 2;
    const int bh = blockIdx.x, b = bh >> 3, h = bh & 7;
    const int q0 = blockIdx.y * 256;

    const int nv = nvalid[b];
    const int nt = (nv + 127) >> 7;      // tiles per half
    const int kvofs = half * 64 * nt;    // this wave's compacted-key offset

    bf16x8 qf[4][2];
    #pragma unroll
    for (int qs = 0; qs < 4; ++qs) {
        size_t qb = ((size_t)bh * 2048 + q0 + w4 * 64 + qs * 16 + l15) * 64 + quad * 8;
        qf[qs][0] = *(const bf16x8*)(Qh + qb);
        qf[qs][1] = *(const bf16x8*)(Qh + qb + 32);
    }

    const f32x4 z = {0.f, 0.f, 0.f, 0.f};
    f32x4 oacc[4][4];
    #pragma unroll
    for (int i = 0; i < 4; ++i)
        #pragma unroll
        for (int j = 0; j < 4; ++j) oacc[i][j] = z;
    float lacc[4] = {0.f, 0.f, 0.f, 0.f};

    // staging: 4 async16/thread/t. Regions cc = wave*4+i: hc = cc>>4 (half),
    // pc = (cc>>3)&1 (0=K,1=V), ic = cc&7 (8-row block). chunk^=row&7 (gsw).
    const int rloc = lane >> 3, gsw = (lane & 7) ^ rloc;
    const ushort* sb[4]; size_t sstep[4]; int dofs[4];
    #pragma unroll
    for (int i = 0; i < 4; ++i) {
        int cc = wave * 4 + i;
        int hc = cc >> 4, r16 = cc & 15, pc = r16 >> 3, ic = r16 & 7;
        if (pc == 0) {
            sb[i] = Kh + ((size_t)(bh * 2048 + hc * 64 * nt + ic * 8 + rloc)) * 64 + gsw * 8;
            sstep[i] = (size_t)64 * 64;
        } else {
            sb[i] = VhT + ((size_t)(bh * 64 + ic * 8 + rloc)) * 2048 + hc * 64 * nt + gsw * 8;
            sstep[i] = 64;
        }
        dofs[i] = (hc * 2 + pc) * 4096 + ic * 512;
    }

    const int sw0 = (quad ^ (l15 & 7)) * 8;
    const float SCL = 0.18033688011112042f;   // 0.125 * log2(e)

    if (nt > 0) {
        #pragma unroll
        for (int i = 0; i < 4; ++i)
            async16(sb[i], &smem.p1.KVs[0][0][0] + dofs[i]);
    }

    for (int t = 0; t < nt; ++t) {
        __syncthreads();
        if (t + 1 < nt) {
            #pragma unroll
            for (int i = 0; i < 4; ++i)
                async16(sb[i] + (size_t)(t + 1) * sstep[i], &smem.p1.KVs[(t + 1) & 1][0][0] + dofs[i]);
        }
        const int p = t & 1;
        const ushort* K0 = smem.p1.KVs[p][half * 2 + 0];
        const ushort* V0 = smem.p1.KVs[p][half * 2 + 1];
        ushort* Pw = smem.p1.Pp[wave];

        #pragma unroll
        for (int ks = 0; ks < 2; ++ks) {
            #pragma unroll
            for (int kt2 = 0; kt2 < 2; ++kt2) {
                const int kt = ks * 2 + kt2;
                const int kb = (kt * 16 + l15) * 64;
                bf16x8 ka0 = *(const bf16x8*)&K0[kb + sw0];
                bf16x8 ka1 = *(const bf16x8*)&K0[kb + (sw0 ^ 32)];
                const int kbase = kvofs + t * 64 + kt * 16 + quad * 4;
                float bias[4];   // log2-domain tail bias (replaces mask loads)
                #pragma unroll
                for (int r = 0; r < 4; ++r) bias[r] = (kbase + r < nv) ? 0.f : -1e38f;
                #pragma unroll
                for (int qs = 0; qs < 4; ++qs) {
                    f32x4 a = z;
                    a = MFMA16(ka0, qf[qs][0], a);
                    a = MFMA16(ka1, qf[qs][1], a);
                    float pv[4];
                    #pragma unroll
                    for (int r = 0; r < 4; ++r) {
                        float x = __builtin_fmaf(a[r], SCL, bias[r]);
                        float e; asm("v_exp_f32 %0, %1" : "=v"(e) : "v"(x));
                        lacc[qs] += e;
                        pv[r] = e;
                    }
                    unsigned u01, u23;
                    asm("v_cvt_pk_bf16_f32 %0, %1, %2" : "=v"(u01) : "v"(pv[0]), "v"(pv[1]));
                    asm("v_cvt_pk_bf16_f32 %0, %1, %2" : "=v"(u23) : "v"(pv[2]), "v"(pv[3]));
                    uint2 w2; w2.x = u01; w2.y = u23;
                    *(uint2*)&Pw[(qs * 16 + l15) * LDP6 + kt2 * 16 + quad * 4] = w2;
                }
            }
            const int svo = sw0 ^ (ks * 32);
            bf16x8 pf[4];
            #pragma unroll
            for (int qs = 0; qs < 4; ++qs)
                pf[qs] = *(const bf16x8*)&Pw[(qs * 16 + l15) * LDP6 + quad * 8];
            #pragma unroll
            for (int dsub = 0; dsub < 4; ++dsub) {
                const int vb = (dsub * 16 + l15) * 64;
                bf16x8 vh = *(const bf16x8*)&V0[vb + svo];
                #pragma unroll
                for (int qs = 0; qs < 4; ++qs)
                    oacc[qs][dsub] = MFMA16(vh, pf[qs], oacc[qs][dsub]);
            }
        }
    }

    float lv[4];
    #pragma unroll
    for (int qs = 0; qs < 4; ++qs) {
        float v = lacc[qs];
        v += __shfl_xor(v, 16);
        v += __shfl_xor(v, 32);
        lv[qs] = v;
    }

    __syncthreads();
    if (half == 1) {
        #pragma unroll
        for (int qs = 0; qs < 4; ++qs) {
            #pragma unroll
            for (int dsub = 0; dsub < 4; ++dsub) {
                float4 o4 = {oacc[qs][dsub][0], oacc[qs][dsub][1], oacc[qs][dsub][2], oacc[qs][dsub][3]};
                *(float4*)&smem.p2.Obuf[w4][(qs * 16 + l15) * 68 + dsub * 16 + quad * 4] = o4;
            }
            if (quad == 0) smem.p2.Lbuf[w4][qs * 16 + l15] = lv[qs];
        }
    }
    __syncthreads();
    if (half == 0) {
        #pragma unroll
        for (int qs = 0; qs < 4; ++qs) {
            float ltot = lv[qs] + smem.p2.Lbuf[w4][qs * 16 + l15];
            float inv = (ltot > 0.f) ? 1.f / ltot : 0.f;
            int row = q0 + w4 * 64 + qs * 16 + l15;
            ushort* rph = XSh + ((size_t)(b * 2048 + row)) * 512 + h * 64;
            ushort* rpl = XSl + ((size_t)(b * 2048 + row)) * 512 + h * 64;
            #pragma unroll
            for (int dsub = 0; dsub < 4; ++dsub) {
                float4 p4 = *(const float4*)&smem.p2.Obuf[w4][(qs * 16 + l15) * 68 + dsub * 16 + quad * 4];
                float s0 = (oacc[qs][dsub][0] + p4.x) * inv;
                float s1 = (oacc[qs][dsub][1] + p4.y) * inv;
                float s2 = (oacc[qs][dsub][2] + p4.z) * inv;
                float s3 = (oacc[qs][dsub][3] + p4.w) * inv;
                ushort4 hv, lv4;
                splitbf(s0, hv.x, lv4.x); splitbf(s1, hv.y, lv4.y);
                splitbf(s2, hv.z, lv4.z); splitbf(s3, hv.w, lv4.w);
                *(ushort4*)&rph[dsub * 16 + quad * 4] = hv;
                *(ushort4*)&rpl[dsub * 16 + quad * 4] = lv4;
            }
        }
    }
}

extern "C" void kernel_launch(void* const* d_in, const int* in_sizes, int n_in,
                              void* d_out, int out_size, void* d_ws, size_t ws_size,
                              hipStream_t stream) {
    const float* query = (const float*)d_in[0];
    const float* key   = (const float*)d_in[1];
    const float* value = (const float*)d_in[2];
    const int*   mask  = (const int*)d_in[3];
    const float* Wq = (const float*)d_in[4];
    const float* bq = (const float*)d_in[5];
    const float* Wk = (const float*)d_in[6];
    const float* bk = (const float*)d_in[7];
    const float* Wv = (const float*)d_in[8];
    const float* bv = (const float*)d_in[9];
    const float* Wo = (const float*)d_in[10];
    const float* bo = (const float*)d_in[11];

    char* w = (char*)d_ws;
    const size_t MB = (size_t)1 << 20;
    ushort* Qh  = (ushort*)(w + 0 * MB);    // 8 MB
    ushort* Khp = (ushort*)(w + 16 * MB);   // 8 MB
    ushort* VhT = (ushort*)(w + 24 * MB);   // 8 MB
    ushort* Xh3 = (ushort*)(w + 40 * MB);   // [3][8192][512], 24MB, dead after gemm#1
    ushort* Xl3 = (ushort*)(w + 64 * MB);   // 24MB, dead after gemm#1
    ushort* XSh = (ushort*)(w + 56 * MB);   // 8MB, overlays Xh3 tail (temporally disjoint)
    ushort* XSl = (ushort*)(w + 64 * MB);   // 8MB, overlays Xl3 head (temporally disjoint)
    ushort* WTh = (ushort*)(w + 88 * MB);   // [2048][512] = 2 MB (z=0..3: Wq,Wk,Wv,Wo)
    ushort* WTl = (ushort*)(w + 90 * MB);   // 2 MB
    int* idxbuf = (int*)(w + 92 * MB);      // [4][2048] int, 32 KB
    int* nvbuf  = (int*)(w + 92 * MB + 65536);

    maskscan_kernel<<<dim3(4), 256, 0, stream>>>(mask, idxbuf, nvbuf);
    xsplit3_kernel<<<dim3(2048, 1, 3), 256, 0, stream>>>(query, key, value, idxbuf, Xh3, Xl3);
    wsplit4_kernel<<<dim3(8, 8, 4), 256, 0, stream>>>(Wq, Wk, Wv, Wo, WTh, WTl);
    gemm2_kernel<<<dim3(64, 24), 256, 0, stream>>>(
        Xh3, Xl3, WTh, WTl, bq, bk, bv, nvbuf, 0, nullptr, Qh, Khp, VhT);
    attn3_kernel<<<dim3(32, 8), 512, 0, stream>>>(Qh, Khp, VhT, nvbuf, XSh, XSl);
    gemm2_kernel<<<dim3(64, 8), 256, 0, stream>>>(
        XSh, XSl, WTh + (size_t)1536 * 512, WTl + (size_t)1536 * 512,
        bo, bo, bo, nvbuf, 1, (float*)d_out,
        nullptr, nullptr, nullptr);
}

// Round 11
// 203.695 us; speedup vs baseline: 1.4732x; 1.0922x over previous
//
#include <hip/hip_runtime.h>
#include <math.h>

#define Bq 4
#define Lq 2048
#define NH 8
#define LDP6 36   // attn Pp row stride (ushorts): 72B = 18 banks, gcd(18,32)=2 -> conflict-free

typedef __attribute__((ext_vector_type(8))) __bf16 bf16x8;
typedef __attribute__((ext_vector_type(4))) float f32x4;
#define MFMA16(a,b,c) __builtin_amdgcn_mfma_f32_16x16x32_bf16(a,b,c,0,0,0)

__device__ __forceinline__ void async16(const void* g, void* l) {
    __builtin_amdgcn_global_load_lds(
        (const __attribute__((address_space(1))) unsigned int*)g,
        (__attribute__((address_space(3))) unsigned int*)l, 16, 0, 0);
}

// truncation split: x = hi + lo (+ ~2^-16 rel residual)
__device__ __forceinline__ void splitbf(float x, ushort& h, ushort& l) {
    unsigned u = __float_as_uint(x);
    h = (ushort)(u >> 16);
    float hf = __uint_as_float(u & 0xffff0000u);
    l = (ushort)(__float_as_uint(x - hf) >> 16);
}
// round-to-nearest-even bf16
__device__ __forceinline__ ushort rnebf(float x) {
    unsigned u = __float_as_uint(x);
    return (ushort)((u + 0x7fffu + ((u >> 16) & 1u)) >> 16);
}

// ---- per-batch mask compaction: idx[b][j] = j-th valid key position, nvalid[b] ----
__global__ __launch_bounds__(256) void maskscan_kernel(
    const int* __restrict__ mask, int* __restrict__ idx, int* __restrict__ nvalid)
{
    __shared__ int ss[256];
    const int b = blockIdx.x, tid = threadIdx.x;
    int m[8], s = 0;
    #pragma unroll
    for (int j = 0; j < 8; ++j) { m[j] = (mask[b * 2048 + tid * 8 + j] != 0); s += m[j]; }
    int v = s;
    ss[tid] = v;
    __syncthreads();
    for (int off = 1; off < 256; off <<= 1) {
        int t_ = (tid >= off) ? ss[tid - off] : 0;
        __syncthreads();
        v += t_;
        ss[tid] = v;
        __syncthreads();
    }
    int pos = v - s;   // exclusive prefix
    #pragma unroll
    for (int j = 0; j < 8; ++j) if (m[j]) idx[b * 2048 + pos++] = tid * 8 + j;
    int tot = ss[255];
    if (tid == 0) nvalid[b] = tot;
    for (int k = tot + tid; k < 2048; k += 256) idx[b * 2048 + k] = 0;   // pad -> row 0 (finite)
}

// ---- X [8192][512] fp32 -> Xr [z][8192][512] single RNE bf16 plane ----
// z=0 (query): direct. z=1,2 (key,value): rows GATHERED through idx; rows
// beyond ceil128(nvalid) skipped entirely (never staged by gemm).
__global__ __launch_bounds__(256) void xrne3_kernel(
    const float* __restrict__ X0, const float* __restrict__ X1, const float* __restrict__ X2,
    const int* __restrict__ idx, const int* __restrict__ nvalid,
    ushort* __restrict__ Xr)
{
    const int z = blockIdx.z;
    const float* X = (z == 0) ? X0 : (z == 1) ? X1 : X2;
    const size_t ebase = (size_t)blockIdx.x * 2048 + (size_t)threadIdx.x * 8;
    const int row = (int)(ebase >> 9), col = (int)(ebase & 511);
    const int b = row >> 11, r = row & 2047;
    if (z >= 1) {
        int nv = nvalid[b];
        int nvpad = ((nv + 127) >> 7) << 7;
        if (r >= nvpad) return;
    }
    const int srow = (z == 0) ? row : (b * 2048 + idx[b * 2048 + r]);
    const float* src = X + (size_t)srow * 512 + col;
    float4 a = *(const float4*)(src);
    float4 bb = *(const float4*)(src + 4);
    float vv[8] = {a.x, a.y, a.z, a.w, bb.x, bb.y, bb.z, bb.w};
    ushort hs[8];
    #pragma unroll
    for (int j = 0; j < 8; ++j) hs[j] = rnebf(vv[j]);
    uint4 wh;
    wh.x = hs[0] | ((unsigned)hs[1] << 16); wh.y = hs[2] | ((unsigned)hs[3] << 16);
    wh.z = hs[4] | ((unsigned)hs[5] << 16); wh.w = hs[6] | ((unsigned)hs[7] << 16);
    *(uint4*)(Xr + (size_t)z * 8192 * 512 + ebase) = wh;
}

// ---- W [512k][512n] fp32 -> WT [z*512 + n][k] bf16 hi/lo planes (z=0..3: Wq,Wk,Wv,Wo) ----
__global__ __launch_bounds__(256) void wsplit4_kernel(
    const float* __restrict__ W0, const float* __restrict__ W1,
    const float* __restrict__ W2, const float* __restrict__ W3,
    ushort* __restrict__ WTh, ushort* __restrict__ WTl)
{
    __shared__ float T[64][65];
    const int z = blockIdx.z;
    const float* W = (z == 0) ? W0 : (z == 1) ? W1 : (z == 2) ? W2 : W3;
    const int k0 = blockIdx.x * 64, n0 = blockIdx.y * 64;
    const int tid = threadIdx.x;
    #pragma unroll
    for (int i = 0; i < 4; ++i) {
        int u = tid + i * 256;
        int row = u >> 4, c4 = (u & 15) * 4;
        float4 v = *(const float4*)(W + (size_t)(k0 + row) * 512 + n0 + c4);
        T[row][c4 + 0] = v.x; T[row][c4 + 1] = v.y; T[row][c4 + 2] = v.z; T[row][c4 + 3] = v.w;
    }
    __syncthreads();
    #pragma unroll
    for (int i = 0; i < 2; ++i) {
        int u = tid + i * 256;
        int d = u >> 3, c8 = (u & 7) * 8;
        ushort hs[8], ls[8];
        #pragma unroll
        for (int j = 0; j < 8; ++j) splitbf(T[c8 + j][d], hs[j], ls[j]);
        uint4 wh, wl;
        wh.x = hs[0] | ((unsigned)hs[1] << 16); wh.y = hs[2] | ((unsigned)hs[3] << 16);
        wh.z = hs[4] | ((unsigned)hs[5] << 16); wh.w = hs[6] | ((unsigned)hs[7] << 16);
        wl.x = ls[0] | ((unsigned)ls[1] << 16); wl.y = ls[2] | ((unsigned)ls[3] << 16);
        wl.z = ls[4] | ((unsigned)ls[5] << 16); wl.w = ls[6] | ((unsigned)ls[7] << 16);
        size_t off = (size_t)(z * 512 + n0 + d) * 512 + k0 + c8;
        *(uint4*)(WTh + off) = wh;
        *(uint4*)(WTl + off) = wl;
    }
}

// ---- GEMM3: 128x128 tile, BK=32, 4 waves (64x64 each), dbuf fully-async ----
// A = single RNE bf16 plane (2 MFMA per ms/ns: a x (Bh + Bl)); B = hi/lo split.
// 32 MFMA/wave/phase (2x r10), half the blocks -> half the barrier drains.
// K/V blocks (mi>=1) early-exit beyond ceil128(nvalid[b]). LDS 48 KB.
union GS {
    struct {
        ushort A[2][4096];    // 128 rows x 32 k
        ushort Bh[2][4096];   // 128 cols x 32 k
        ushort Bl[2][4096];
    } s;
    ushort E[24576];          // epilogue scratch (uses 17408)
};

__global__ __launch_bounds__(256) void gemm2_kernel(
    const ushort* __restrict__ Ap,
    const ushort* __restrict__ BhT, const ushort* __restrict__ BlT,
    const float* __restrict__ b0, const float* __restrict__ b1, const float* __restrict__ b2,
    const int* __restrict__ nvalid, int final_, float* __restrict__ Cf,
    ushort* __restrict__ Qh, ushort* __restrict__ Khp, ushort* __restrict__ VhT)
{
    __shared__ __align__(16) GS gs;
    const int tid = threadIdx.x;
    const int wave = tid >> 6, lane = tid & 63;
    const int l15 = lane & 15, quad = lane >> 4;
    const int m0 = blockIdx.x * 128;
    const int yy = blockIdx.y;
    const int mi = yy >> 2, n0 = (yy & 3) * 128;
    const int nglob = mi * 512 + n0;

    if (!final_ && mi >= 1) {   // uniform early-exit: compacted K/V rows only
        int nv = nvalid[m0 >> 11];
        int nvpad = ((nv + 127) >> 7) << 7;
        if ((m0 & 2047) >= nvpad) return;
    }

    const float* bias = (mi == 0) ? b0 : (mi == 1) ? b1 : b2;
    const int wm = (wave & 1) * 64, wn = (wave >> 1) * 64;

    // A staging: 8 blocks of 16 rows; wave handles rb = wave*2 + j
    const ushort* AZ = Ap + (size_t)mi * 8192 * 512;
    const int arow = lane >> 2;
    const int acs = ((lane & 3) ^ ((arow >> 1) & 3)) * 8;   // src pre-swizzle = read swizzle
    const ushort* asrc[2]; int adst[2];
    #pragma unroll
    for (int j = 0; j < 2; ++j) {
        int rb = wave * 2 + j;
        asrc[j] = AZ + (size_t)(m0 + rb * 16 + arow) * 512 + acs;
        adst[j] = rb * 512 + lane * 8;
    }
    // B staging: 128 rows x 2 planes; wave handles rows wave*32 + j*16 + brow
    const int brow = lane >> 2;
    const int bcs = ((lane & 3) ^ (brow & 3)) * 8;
    const ushort* bsh[2]; const ushort* bsl[2]; int bdst[2];
    #pragma unroll
    for (int j = 0; j < 2; ++j) {
        int r2 = wave * 32 + j * 16 + brow;
        bsh[j] = BhT + (size_t)(nglob + r2) * 512 + bcs;
        bsl[j] = BlT + (size_t)(nglob + r2) * 512 + bcs;
        bdst[j] = wave * 1024 + j * 512 + lane * 8;
    }

    f32x4 acc[4][4];
    #pragma unroll
    for (int i = 0; i < 4; ++i)
        #pragma unroll
        for (int j = 0; j < 4; ++j) acc[i][j] = (f32x4){0.f, 0.f, 0.f, 0.f};

    #pragma unroll
    for (int j = 0; j < 2; ++j) {
        async16(asrc[j], &gs.s.A[0][adst[j]]);
        async16(bsh[j], &gs.s.Bh[0][bdst[j]]);
        async16(bsl[j], &gs.s.Bl[0][bdst[j]]);
    }

    for (int t = 0; t < 16; ++t) {
        const int p = t & 1;
        __syncthreads();
        if (t < 15) {
            const int kn = (t + 1) * 32;
            #pragma unroll
            for (int j = 0; j < 2; ++j) {
                async16(asrc[j] + kn, &gs.s.A[1 - p][adst[j]]);
                async16(bsh[j] + kn, &gs.s.Bh[1 - p][bdst[j]]);
                async16(bsl[j] + kn, &gs.s.Bl[1 - p][bdst[j]]);
            }
        }
        bf16x8 af[4];
        #pragma unroll
        for (int ms = 0; ms < 4; ++ms) {
            int off = (wm + ms * 16 + l15) * 32 + (quad ^ ((l15 >> 1) & 3)) * 8;
            af[ms] = *(const bf16x8*)&gs.s.A[p][off];
        }
        #pragma unroll
        for (int ns = 0; ns < 4; ++ns) {
            int off = (wn + ns * 16 + l15) * 32 + (quad ^ (l15 & 3)) * 8;
            bf16x8 bfh = *(const bf16x8*)&gs.s.Bh[p][off];
            bf16x8 bfl = *(const bf16x8*)&gs.s.Bl[p][off];
            #pragma unroll
            for (int ms = 0; ms < 4; ++ms) {
                acc[ms][ns] = MFMA16(af[ms], bfl, acc[ms][ns]);
                acc[ms][ns] = MFMA16(af[ms], bfh, acc[ms][ns]);
            }
        }
    }

    // bias
    #pragma unroll
    for (int ns = 0; ns < 4; ++ns) {
        float bv = bias[n0 + wn + ns * 16 + l15];
        #pragma unroll
        for (int ms = 0; ms < 4; ++ms)
            #pragma unroll
            for (int r = 0; r < 4; ++r) acc[ms][ns][r] += bv;
    }

    if (final_) {   // coalesced fp32 stores
        #pragma unroll
        for (int ns = 0; ns < 4; ++ns) {
            int col = n0 + wn + ns * 16 + l15;
            #pragma unroll
            for (int ms = 0; ms < 4; ++ms)
                #pragma unroll
                for (int r = 0; r < 4; ++r)
                    Cf[(size_t)(m0 + wm + ms * 16 + quad * 4 + r) * 512 + col] = acc[ms][ns][r];
        }
        return;
    }

    const int h0 = n0 >> 6;                  // 0,2,4,6 (two heads per block)
    const int b = m0 >> 11, rr0 = m0 & 2047;
    __syncthreads();
    // acc -> E, single-pass RNE (V: transposed [col][row]; Q/K: row-major)
    #pragma unroll
    for (int ms = 0; ms < 4; ++ms) {
        #pragma unroll
        for (int ns = 0; ns < 4; ++ns) {
            int cl = wn + ns * 16 + l15;
            int rl = wm + ms * 16 + quad * 4;
            if (mi == 2) {
                ushort4 w4;
                #pragma unroll
                for (int r = 0; r < 4; ++r) ((ushort*)&w4)[r] = rnebf(acc[ms][ns][r]);
                *(ushort4*)&gs.E[cl * 136 + rl] = w4;
            } else {
                #pragma unroll
                for (int r = 0; r < 4; ++r) gs.E[(rl + r) * 136 + cl] = rnebf(acc[ms][ns][r]);
            }
        }
    }
    __syncthreads();
    if (mi == 2) {
        #pragma unroll
        for (int i = 0; i < 8; ++i) {
            int idx2 = tid + i * 256;
            int d = idx2 >> 4, rg = idx2 & 15;
            int head = d >> 6, dd = d & 63;
            uint4 u = *(const uint4*)&gs.E[d * 136 + rg * 8];
            *(uint4*)&VhT[((size_t)(b * 8 + h0 + head) * 64 + dd) * 2048 + rr0 + rg * 8] = u;
        }
    } else {
        ushort* dst = (mi == 0) ? Qh : Khp;
        #pragma unroll
        for (int i = 0; i < 8; ++i) {
            int idx2 = tid + i * 256;
            int row = idx2 >> 4, cg = idx2 & 15;
            int head = cg >> 3, c8 = (cg & 7) * 8;
            uint4 u = *(const uint4*)&gs.E[row * 136 + cg * 8];
            *(uint4*)&dst[((size_t)(b * 8 + h0 + head) * 2048 + rr0 + row) * 64 + c8] = u;
        }
    }
}

// ---- Flash attention over COMPACTED keys, single-plane Q/K/V, RNE XS out ----
union SmemU {
    struct { ushort KVs[2][4][4096]; ushort Pp[8][64 * LDP6]; } p1;
    struct { float Obuf[4][64 * 68]; float Lbuf[4][64]; } p2;
};

__global__ __launch_bounds__(512, 2) void attn3_kernel(
    const ushort* __restrict__ Qh, const ushort* __restrict__ Kh,
    const ushort* __restrict__ VhT, const int* __restrict__ nvalid,
    ushort* __restrict__ XS)
{
    __shared__ SmemU smem;
    const int tid = threadIdx.x;
    const int wave = tid >> 6, lane = tid & 63;
    const int l15 = lane & 15, quad = lane >> 4;
    const int w4 = wave & 3, half = wave >> 2;
    const int bh = blockIdx.x, b = bh >> 3, h = bh & 7;
    const int q0 = blockIdx.y * 256;

    const int nv = nvalid[b];
    const int nt = (nv + 127) >> 7;      // tiles per half
    const int kvofs = half * 64 * nt;    // this wave's compacted-key offset

    bf16x8 qf[4][2];
    #pragma unroll
    for (int qs = 0; qs < 4; ++qs) {
        size_t qb = ((size_t)bh * 2048 + q0 + w4 * 64 + qs * 16 + l15) * 64 + quad * 8;
        qf[qs][0] = *(const bf16x8*)(Qh + qb);
        qf[qs][1] = *(const bf16x8*)(Qh + qb + 32);
    }

    const f32x4 z = {0.f, 0.f, 0.f, 0.f};
    f32x4 oacc[4][4];
    #pragma unroll
    for (int i = 0; i < 4; ++i)
        #pragma unroll
        for (int j = 0; j < 4; ++j) oacc[i][j] = z;
    float lacc[4] = {0.f, 0.f, 0.f, 0.f};

    const int rloc = lane >> 3, gsw = (lane & 7) ^ rloc;
    const ushort* sb[4]; size_t sstep[4]; int dofs[4];
    #pragma unroll
    for (int i = 0; i < 4; ++i) {
        int cc = wave * 4 + i;
        int hc = cc >> 4, r16 = cc & 15, pc = r16 >> 3, ic = r16 & 7;
        if (pc == 0) {
            sb[i] = Kh + ((size_t)(bh * 2048 + hc * 64 * nt + ic * 8 + rloc)) * 64 + gsw * 8;
            sstep[i] = (size_t)64 * 64;
        } else {
            sb[i] = VhT + ((size_t)(bh * 64 + ic * 8 + rloc)) * 2048 + hc * 64 * nt + gsw * 8;
            sstep[i] = 64;
        }
        dofs[i] = (hc * 2 + pc) * 4096 + ic * 512;
    }

    const int sw0 = (quad ^ (l15 & 7)) * 8;
    const float SCL = 0.18033688011112042f;   // 0.125 * log2(e)

    if (nt > 0) {
        #pragma unroll
        for (int i = 0; i < 4; ++i)
            async16(sb[i], &smem.p1.KVs[0][0][0] + dofs[i]);
    }

    for (int t = 0; t < nt; ++t) {
        __syncthreads();
        if (t + 1 < nt) {
            #pragma unroll
            for (int i = 0; i < 4; ++i)
                async16(sb[i] + (size_t)(t + 1) * sstep[i], &smem.p1.KVs[(t + 1) & 1][0][0] + dofs[i]);
        }
        const int p = t & 1;
        const ushort* K0 = smem.p1.KVs[p][half * 2 + 0];
        const ushort* V0 = smem.p1.KVs[p][half * 2 + 1];
        ushort* Pw = smem.p1.Pp[wave];

        #pragma unroll
        for (int ks = 0; ks < 2; ++ks) {
            #pragma unroll
            for (int kt2 = 0; kt2 < 2; ++kt2) {
                const int kt = ks * 2 + kt2;
                const int kb = (kt * 16 + l15) * 64;
                bf16x8 ka0 = *(const bf16x8*)&K0[kb + sw0];
                bf16x8 ka1 = *(const bf16x8*)&K0[kb + (sw0 ^ 32)];
                const int kbase = kvofs + t * 64 + kt * 16 + quad * 4;
                float bias[4];   // log2-domain tail bias (replaces mask loads)
                #pragma unroll
                for (int r = 0; r < 4; ++r) bias[r] = (kbase + r < nv) ? 0.f : -1e38f;
                #pragma unroll
                for (int qs = 0; qs < 4; ++qs) {
                    f32x4 a = z;
                    a = MFMA16(ka0, qf[qs][0], a);
                    a = MFMA16(ka1, qf[qs][1], a);
                    float pv[4];
                    #pragma unroll
                    for (int r = 0; r < 4; ++r) {
                        float x = __builtin_fmaf(a[r], SCL, bias[r]);
                        float e; asm("v_exp_f32 %0, %1" : "=v"(e) : "v"(x));
                        lacc[qs] += e;
                        pv[r] = e;
                    }
                    unsigned u01, u23;
                    asm("v_cvt_pk_bf16_f32 %0, %1, %2" : "=v"(u01) : "v"(pv[0]), "v"(pv[1]));
                    asm("v_cvt_pk_bf16_f32 %0, %1, %2" : "=v"(u23) : "v"(pv[2]), "v"(pv[3]));
                    uint2 w2; w2.x = u01; w2.y = u23;
                    *(uint2*)&Pw[(qs * 16 + l15) * LDP6 + kt2 * 16 + quad * 4] = w2;
                }
            }
            const int svo = sw0 ^ (ks * 32);
            bf16x8 pf[4];
            #pragma unroll
            for (int qs = 0; qs < 4; ++qs)
                pf[qs] = *(const bf16x8*)&Pw[(qs * 16 + l15) * LDP6 + quad * 8];
            #pragma unroll
            for (int dsub = 0; dsub < 4; ++dsub) {
                const int vb = (dsub * 16 + l15) * 64;
                bf16x8 vh = *(const bf16x8*)&V0[vb + svo];
                #pragma unroll
                for (int qs = 0; qs < 4; ++qs)
                    oacc[qs][dsub] = MFMA16(vh, pf[qs], oacc[qs][dsub]);
            }
        }
    }

    float lv[4];
    #pragma unroll
    for (int qs = 0; qs < 4; ++qs) {
        float v = lacc[qs];
        v += __shfl_xor(v, 16);
        v += __shfl_xor(v, 32);
        lv[qs] = v;
    }

    __syncthreads();
    if (half == 1) {
        #pragma unroll
        for (int qs = 0; qs < 4; ++qs) {
            #pragma unroll
            for (int dsub = 0; dsub < 4; ++dsub) {
                float4 o4 = {oacc[qs][dsub][0], oacc[qs][dsub][1], oacc[qs][dsub][2], oacc[qs][dsub][3]};
                *(float4*)&smem.p2.Obuf[w4][(qs * 16 + l15) * 68 + dsub * 16 + quad * 4] = o4;
            }
            if (quad == 0) smem.p2.Lbuf[w4][qs * 16 + l15] = lv[qs];
        }
    }
    __syncthreads();
    if (half == 0) {
        #pragma unroll
        for (int qs = 0; qs < 4; ++qs) {
            float ltot = lv[qs] + smem.p2.Lbuf[w4][qs * 16 + l15];
            float inv = (ltot > 0.f) ? 1.f / ltot : 0.f;
            int row = q0 + w4 * 64 + qs * 16 + l15;
            ushort* rp = XS + ((size_t)(b * 2048 + row)) * 512 + h * 64;
            #pragma unroll
            for (int dsub = 0; dsub < 4; ++dsub) {
                float4 p4 = *(const float4*)&smem.p2.Obuf[w4][(qs * 16 + l15) * 68 + dsub * 16 + quad * 4];
                ushort4 hv;
                hv.x = rnebf((oacc[qs][dsub][0] + p4.x) * inv);
                hv.y = rnebf((oacc[qs][dsub][1] + p4.y) * inv);
                hv.z = rnebf((oacc[qs][dsub][2] + p4.z) * inv);
                hv.w = rnebf((oacc[qs][dsub][3] + p4.w) * inv);
                *(ushort4*)&rp[dsub * 16 + quad * 4] = hv;
            }
        }
    }
}

extern "C" void kernel_launch(void* const* d_in, const int* in_sizes, int n_in,
                              void* d_out, int out_size, void* d_ws, size_t ws_size,
                              hipStream_t stream) {
    const float* query = (const float*)d_in[0];
    const float* key   = (const float*)d_in[1];
    const float* value = (const float*)d_in[2];
    const int*   mask  = (const int*)d_in[3];
    const float* Wq = (const float*)d_in[4];
    const float* bq = (const float*)d_in[5];
    const float* Wk = (const float*)d_in[6];
    const float* bk = (const float*)d_in[7];
    const float* Wv = (const float*)d_in[8];
    const float* bv = (const float*)d_in[9];
    const float* Wo = (const float*)d_in[10];
    const float* bo = (const float*)d_in[11];

    char* w = (char*)d_ws;
    const size_t MB = (size_t)1 << 20;
    ushort* Qh  = (ushort*)(w + 0 * MB);    // 8 MB
    ushort* XS  = (ushort*)(w + 8 * MB);    // 8 MB (attn out, single RNE plane)
    ushort* Khp = (ushort*)(w + 16 * MB);   // 8 MB
    ushort* VhT = (ushort*)(w + 24 * MB);   // 8 MB
    ushort* Xr  = (ushort*)(w + 32 * MB);   // [3][8192][512] = 48 MB, dead after gemm#1
    ushort* WTh = (ushort*)(w + 80 * MB);   // [2048][512] = 2 MB (z=0..3: Wq,Wk,Wv,Wo)
    ushort* WTl = (ushort*)(w + 82 * MB);   // 2 MB
    int* idxbuf = (int*)(w + 84 * MB);      // [4][2048] int, 32 KB
    int* nvbuf  = (int*)(w + 84 * MB + 65536);

    maskscan_kernel<<<dim3(4), 256, 0, stream>>>(mask, idxbuf, nvbuf);
    xrne3_kernel<<<dim3(2048, 1, 3), 256, 0, stream>>>(query, key, value, idxbuf, nvbuf, Xr);
    wsplit4_kernel<<<dim3(8, 8, 4), 256, 0, stream>>>(Wq, Wk, Wv, Wo, WTh, WTl);
    gemm2_kernel<<<dim3(64, 12), 256, 0, stream>>>(
        Xr, WTh, WTl, bq, bk, bv, nvbuf, 0, nullptr, Qh, Khp, VhT);
    attn3_kernel<<<dim3(32, 8), 512, 0, stream>>>(Qh, Khp, VhT, nvbuf, XS);
    gemm2_kernel<<<dim3(64, 4), 256, 0, stream>>>(
        XS, WTh + (size_t)1536 * 512, WTl + (size_t)1536 * 512,
        bo, bo, bo, nvbuf, 1, (float*)d_out,
        nullptr, nullptr, nullptr);
}